// Round 15
// baseline (983.698 us; speedup 1.0000x reference)
//
#include <hip/hip_runtime.h>
#include <hip/hip_bf16.h>
#include <math.h>

typedef __attribute__((ext_vector_type(8))) short bf16x8;
typedef __attribute__((ext_vector_type(4))) float f32x4;
typedef __hip_bfloat16 bf16;

__device__ __forceinline__ void gload_lds16(const void* g, void* l) {
  __builtin_amdgcn_global_load_lds((const __attribute__((address_space(1))) void*)g,
                                   (__attribute__((address_space(3))) void*)l,
                                   16, 0, 0);
}

__device__ __forceinline__ float gelu_erf(float x) {
  return 0.5f * x * (1.0f + erff(x * 0.70710678118654752f));
}

// ---------------- convert f32 -> bf16 (vectorized) ----------------
__global__ __launch_bounds__(256) void k_cvt_bf16(const float* __restrict__ in,
                                                  bf16* __restrict__ out, int n4) {
  int i = blockIdx.x * 256 + threadIdx.x;
  const int stride = gridDim.x * 256;
  for (; i < n4; i += stride) {
    float4 v = reinterpret_cast<const float4*>(in)[i];
    bf16* o = out + (size_t)i * 4;
    o[0] = __float2bfloat16(v.x);
    o[1] = __float2bfloat16(v.y);
    o[2] = __float2bfloat16(v.z);
    o[3] = __float2bfloat16(v.w);
  }
}

// ---------------- concat bq|bk|bv -> cbias[3072] ----------------
__global__ __launch_bounds__(256) void k_concat_bias(const float* __restrict__ bq,
                                                     const float* __restrict__ bk,
                                                     const float* __restrict__ bv,
                                                     float* __restrict__ cbias) {
  const int i = blockIdx.x * 256 + threadIdx.x;  // 0..3071
  const float v = (i < 1024) ? bq[i] : (i < 2048) ? bk[i - 1024] : bv[i - 2048];
  cbias[i] = v;
}

// ---------------- transpose f32 [R][C] -> bf16 [C][R] ----------------
__global__ __launch_bounds__(256) void k_transpose_w(const float* __restrict__ in,
                                                     bf16* __restrict__ out,
                                                     int R, int C) {
  __shared__ float tile[32][33];
  const int c0 = blockIdx.x * 32, r0 = blockIdx.y * 32;
  const int tx = threadIdx.x & 31, ty = threadIdx.x >> 5;
  for (int i = 0; i < 32; i += 8)
    tile[ty + i][tx] = in[(size_t)(r0 + ty + i) * C + c0 + tx];
  __syncthreads();
  for (int i = 0; i < 32; i += 8)
    out[(size_t)(c0 + ty + i) * R + r0 + tx] = __float2bfloat16(tile[tx][ty + i]);
}

// ------------- per-head V transpose: [B*S][E] -> [(b*H+h)*128 + d][S] -------------
__global__ __launch_bounds__(256) void k_transpose_v(const bf16* __restrict__ Vb,
                                                     bf16* __restrict__ Vt) {
  __shared__ bf16 tile[32][34];
  const int bh = blockIdx.z;
  const int b = bh >> 3, h = bh & 7;
  const int s0 = blockIdx.x * 32, d0 = blockIdx.y * 32;
  const int tx = threadIdx.x & 31, ty = threadIdx.x >> 5;
  for (int i = 0; i < 32; i += 8)
    tile[ty + i][tx] = Vb[((size_t)b * 512 + s0 + ty + i) * 1024 + h * 128 + d0 + tx];
  __syncthreads();
  for (int i = 0; i < 32; i += 8)
    Vt[((size_t)bh * 128 + d0 + ty + i) * 512 + s0 + tx] = tile[tx][ty + i];
}

// ======== 128x256 tile, BK=32, 4-wave GEMM, 48KB LDS -> 2 blocks/CU ========
// EPI: 0=bf16, 1=gelu->bf16, 2=f32(+=ACC), 3=bf16 segmented QKV.
// The R14 counters showed all 256^2/128KB variants are WAIT-bound at 1 block/CU
// (MfmaUtil 30%, conflicts 0, HBM 18%). This kernel restores cross-block overlap
// (m97 mechanism): 2 blocks/CU co-resident; when one drains at a barrier the
// other feeds MFMA. Simple 2-barrier loop + counted vmcnt(6) (6 loads/thread/
// tile, depth-1). Swizzle: 16B-slot' = slot ^ ((row>>1)&3) (max 2-way = free);
// read key (lr>>1)&3; staging inverse key (l>>3)&3. LDS slot = A[128r][32k] 8KB
// + B[256r][32k] 16KB = 24KB; 2 slots = 48KB.
template <int EPI, bool ACC>
__global__ __launch_bounds__(256, 2) void k_gemm128x256(
    const bf16* __restrict__ A, const bf16* __restrict__ Bt,
    const float* __restrict__ bias, void* __restrict__ Cout,
    int K, int lda, int ldb, int ldc) {
  __shared__ __attribute__((aligned(16))) char lds[49152];
  const int t = threadIdx.x, w = t >> 6, l = t & 63;
  const int gx = gridDim.x, nwg = gx * gridDim.y;
  int bid = blockIdx.y * gx + blockIdx.x;
  bid = (bid & 7) * (nwg >> 3) + (bid >> 3);  // XCD swizzle (nwg % 8 == 0)
  const int bm = bid / gx, bn = bid % gx;
  const int wm = w >> 1, wn = w & 1;  // 2M x 2N waves; per-wave C = 64x128
  const int lq = l >> 4, lr = l & 15;

  // ---- staging source pointers (inverse-swizzled global; LDS dest linear) ----
  // issue i covers LDS rows i*64 + w*16 + (l>>2); src 16B slot = (l&3)^((l>>3)&3)
  const int srw = w * 16 + (l >> 2);                 // row within 64-row group
  const int scb = (((l & 3) ^ ((l >> 3) & 3)) << 4); // swizzled src byte-in-row
  const size_t la = (size_t)lda * 2, lb = (size_t)ldb * 2;
  const char* Ab = (const char*)(A + (size_t)(bm * 128) * lda);
  const char* Bb = (const char*)(Bt + (size_t)(bn * 256) * ldb);
  const char* pA0 = Ab + (size_t)(srw) * la + scb;
  const char* pA1 = Ab + (size_t)(64 + srw) * la + scb;
  const char* pB0 = Bb + (size_t)(srw) * lb + scb;
  const char* pB1 = Bb + (size_t)(64 + srw) * lb + scb;
  const char* pB2 = Bb + (size_t)(128 + srw) * lb + scb;
  const char* pB3 = Bb + (size_t)(192 + srw) * lb + scb;

  // ---- fragment read offsets (key = (lr>>1)&3, verified fr/fc/wm/wn-indep) ----
  const int swz = (lq ^ ((lr >> 1) & 3)) << 4;
  const int aoff = (wm * 64 + lr) * 64 + swz;           // + fr*1024
  const int boff = 8192 + (wn * 128 + lr) * 64 + swz;   // + fc*1024

  f32x4 acc[4][8];
#pragma unroll
  for (int m = 0; m < 4; ++m)
#pragma unroll
    for (int n = 0; n < 8; ++n) acc[m][n] = (f32x4){0.f, 0.f, 0.f, 0.f};

#define STAGE(slot)                                                       \
  {                                                                       \
    char* dst = lds + (slot) * 24576 + w * 1024;                          \
    gload_lds16(pA0, dst);                                                \
    gload_lds16(pA1, dst + 4096);                                         \
    gload_lds16(pB0, dst + 8192);                                         \
    gload_lds16(pB1, dst + 12288);                                        \
    gload_lds16(pB2, dst + 16384);                                        \
    gload_lds16(pB3, dst + 20480);                                        \
    pA0 += 64; pA1 += 64; pB0 += 64; pB1 += 64; pB2 += 64; pB3 += 64;     \
  }

  const int NT = K >> 5;  // BK=32
  STAGE(0)

  for (int kt = 0; kt < NT; ++kt) {
    if (kt + 1 < NT) {
      STAGE((kt + 1) & 1)
      asm volatile("s_waitcnt vmcnt(6)" ::: "memory");  // tile kt landed; kt+1 in flight
    } else {
      asm volatile("s_waitcnt vmcnt(0)" ::: "memory");
    }
    __builtin_amdgcn_s_barrier();
    asm volatile("" ::: "memory");

    const char* base = lds + (kt & 1) * 24576;
    bf16x8 aF[4], bF[8];
#pragma unroll
    for (int fr = 0; fr < 4; ++fr)
      aF[fr] = *(const bf16x8*)(base + aoff + fr * 1024);
#pragma unroll
    for (int fc = 0; fc < 8; ++fc)
      bF[fc] = *(const bf16x8*)(base + boff + fc * 1024);
    __builtin_amdgcn_s_setprio(1);
#pragma unroll
    for (int fr = 0; fr < 4; ++fr)
#pragma unroll
      for (int fc = 0; fc < 8; ++fc)
        acc[fr][fc] = __builtin_amdgcn_mfma_f32_16x16x32_bf16(aF[fr], bF[fc], acc[fr][fc], 0, 0, 0);
    __builtin_amdgcn_s_setprio(0);
    __builtin_amdgcn_s_barrier();
    asm volatile("" ::: "memory");
  }
#undef STAGE

  // ---- epilogue ----
  const int rowb = bm * 128 + wm * 64;
  const int colb = bn * 256 + wn * 128;
#pragma unroll
  for (int fr = 0; fr < 4; ++fr) {
#pragma unroll
    for (int fc = 0; fc < 8; ++fc) {
      const int col = colb + fc * 16 + lr;
      const float bv = bias ? bias[col] : 0.0f;
#pragma unroll
      for (int i = 0; i < 4; ++i) {
        const int row = rowb + fr * 16 + lq * 4 + i;
        float v = acc[fr][fc][i] + bv;
        if (EPI == 1) v = gelu_erf(v);
        if (EPI <= 1) {
          ((bf16*)Cout)[(size_t)row * ldc + col] = __float2bfloat16(v);
        } else if (EPI == 3) {
          bf16* Cq = (bf16*)Cout + (size_t)(col >> 10) * 16777216ull;
          Cq[(size_t)row * 1024 + (col & 1023)] = __float2bfloat16(v);
        } else {
          float* Cf = (float*)Cout;
          const size_t idx = (size_t)row * ldc + col;
          if (ACC) v += Cf[idx];
          Cf[idx] = v;
        }
      }
    }
  }
}

// ======== attention v5 (frozen: 133us, VGPR 128) ========
__global__ __launch_bounds__(512, 1) void k_attn(const bf16* __restrict__ Qg,
                                                 const bf16* __restrict__ Kg,
                                                 const bf16* __restrict__ Vt,
                                                 bf16* __restrict__ Og) {
  __shared__ __attribute__((aligned(16))) char lds[131072];
  int bid = blockIdx.x;
  bid = (bid & 7) * 128 + (bid >> 3);  // XCD swizzle, 1024 = 8*128
  const int bh = bid >> 2, q0 = (bid & 3) * 128;
  const int b = bh >> 3, h = bh & 7;
  const int t = threadIdx.x, w = t >> 6, l = t & 63;
  const int lq = l >> 4, lr = l & 15;
  const int wm = w >> 2, wn = w & 3;

  const int sr = t >> 4;
  const int ss = (t & 15) ^ (sr & 15);
  {
    const bf16* ks = Kg + ((size_t)b * 512 + sr) * 1024 + h * 128 + ss * 8;
#pragma unroll
    for (int j = 0; j < 16; ++j)
      gload_lds16(ks + (size_t)j * 32 * 1024, lds + j * 8192 + w * 1024);
  }

  bf16x8 qf[4][4];
  {
    const bf16* qb = Qg + ((size_t)b * 512 + q0 + wm * 64 + lr) * 1024 + h * 128 + lq * 8;
#pragma unroll
    for (int fr = 0; fr < 4; ++fr)
#pragma unroll
      for (int d0 = 0; d0 < 4; ++d0)
        qf[fr][d0] = *(const bf16x8*)(qb + (size_t)(fr * 16) * 1024 + d0 * 32);
  }

  asm volatile("s_waitcnt vmcnt(0)" ::: "memory");
  __builtin_amdgcn_s_barrier();
  asm volatile("" ::: "memory");

  f32x4 accS[4][8];
#pragma unroll
  for (int fr = 0; fr < 4; ++fr)
#pragma unroll
    for (int fc = 0; fc < 8; ++fc) accS[fr][fc] = (f32x4){0.f, 0.f, 0.f, 0.f};

  __builtin_amdgcn_s_setprio(1);
#pragma unroll
  for (int fc = 0; fc < 8; ++fc) {
    bf16x8 kf[4];
#pragma unroll
    for (int d0 = 0; d0 < 4; ++d0)
      kf[d0] = *(const bf16x8*)(lds + (wn * 128 + fc * 16 + lr) * 256 +
                                (((d0 * 4 + lq) ^ lr) << 4));
#pragma unroll
    for (int d0 = 0; d0 < 4; ++d0)
#pragma unroll
      for (int fr = 0; fr < 4; ++fr)
        accS[fr][fc] = __builtin_amdgcn_mfma_f32_16x16x32_bf16(qf[fr][d0], kf[d0], accS[fr][fc], 0, 0, 0);
  }
  __builtin_amdgcn_s_setprio(0);

  __builtin_amdgcn_s_barrier();
  asm volatile("" ::: "memory");

  const bf16* vs = Vt + ((size_t)bh * 128 + sr) * 512 + ss * 8;
#define IVC(kc, slot)                                                         \
  {                                                                           \
    _Pragma("unroll") for (int j = 0; j < 4; ++j)                             \
        gload_lds16(vs + (size_t)j * 32 * 512 + (kc) * 128,                   \
                    lds + (slot) * 32768 + j * 8192 + w * 1024);              \
  }
  IVC(0, 0)
  IVC(1, 1)

  float* redm = (float*)(lds + 98304);
  float* reds = (float*)(lds + 100352);
  float fm[4][4];
#pragma unroll
  for (int fr = 0; fr < 4; ++fr)
#pragma unroll
    for (int i = 0; i < 4; ++i) {
      float m = accS[fr][0][i];
#pragma unroll
      for (int fc = 1; fc < 8; ++fc) m = fmaxf(m, accS[fr][fc][i]);
      m = fmaxf(m, __shfl_xor(m, 1));
      m = fmaxf(m, __shfl_xor(m, 2));
      m = fmaxf(m, __shfl_xor(m, 4));
      m = fmaxf(m, __shfl_xor(m, 8));
      if (lr == 0) redm[wn * 128 + wm * 64 + fr * 16 + lq * 4 + i] = m;
    }
  asm volatile("s_waitcnt lgkmcnt(0)" ::: "memory");
  __builtin_amdgcn_s_barrier();
  asm volatile("" ::: "memory");
#pragma unroll
  for (int fr = 0; fr < 4; ++fr)
#pragma unroll
    for (int i = 0; i < 4; ++i) {
      const int row = wm * 64 + fr * 16 + lq * 4 + i;
      fm[fr][i] = fmaxf(fmaxf(redm[row], redm[128 + row]),
                        fmaxf(redm[256 + row], redm[384 + row]));
    }

  f32x4 oacc[4][2];
#pragma unroll
  for (int fr = 0; fr < 4; ++fr)
#pragma unroll
    for (int fc = 0; fc < 2; ++fc) oacc[fr][fc] = (f32x4){0.f, 0.f, 0.f, 0.f};
  float s4[4][4];
#pragma unroll
  for (int fr = 0; fr < 4; ++fr)
#pragma unroll
    for (int i = 0; i < 4; ++i) s4[fr][i] = 0.f;

#define EXPWRITE(kc)                                                           \
  if (wn == (kc)) {                                                            \
    _Pragma("unroll") for (int fr = 0; fr < 4; ++fr)                           \
      _Pragma("unroll") for (int i = 0; i < 4; ++i) {                          \
        const int row = wm * 64 + fr * 16 + lq * 4 + i;                        \
        const int rx = lq * 4 + i;                                             \
        _Pragma("unroll") for (int fc = 0; fc < 8; ++fc) {                     \
          const float e = __expf(accS[fr][fc][i] - fm[fr][i]);                 \
          s4[fr][i] += e;                                                      \
          *(unsigned short*)(lds + 65536 + row * 256 +                         \
                             (((fc * 2 + (lr >> 3)) ^ rx) << 4) + (lr & 7) * 2) = \
              __bfloat16_as_ushort(__float2bfloat16(e));                       \
        }                                                                      \
      }                                                                        \
  }

#define PVMFMA(kc)                                                             \
  {                                                                            \
    const char* Vb = lds + ((kc) & 1) * 32768;                                 \
    __builtin_amdgcn_s_setprio(1);                                             \
    _Pragma("unroll") for (int kk = 0; kk < 4; ++kk) {                         \
      bf16x8 pa[4], vb[2];                                                     \
      _Pragma("unroll") for (int fr = 0; fr < 4; ++fr)                         \
          pa[fr] = *(const bf16x8*)(lds + 65536 + (wm * 64 + fr * 16 + lr) * 256 + \
                                    (((kk * 4 + lq) ^ lr) << 4));              \
      _Pragma("unroll") for (int fc = 0; fc < 2; ++fc)                         \
          vb[fc] = *(const bf16x8*)(Vb + (wn * 32 + fc * 16 + lr) * 256 +      \
                                    (((kk * 4 + lq) ^ lr) << 4));              \
      _Pragma("unroll") for (int fr = 0; fr < 4; ++fr)                         \
        _Pragma("unroll") for (int fc = 0; fc < 2; ++fc)                       \
          oacc[fr][fc] = __builtin_amdgcn_mfma_f32_16x16x32_bf16(pa[fr], vb[fc], oacc[fr][fc], 0, 0, 0); \
    }                                                                          \
    __builtin_amdgcn_s_setprio(0);                                             \
  }

  EXPWRITE(0)
  asm volatile("s_waitcnt lgkmcnt(0)" ::: "memory");
  asm volatile("s_waitcnt vmcnt(4)" ::: "memory");
  __builtin_amdgcn_s_barrier();
  asm volatile("" ::: "memory");
  PVMFMA(0)
  __builtin_amdgcn_s_barrier();
  asm volatile("" ::: "memory");
  IVC(2, 0)
  EXPWRITE(1)
  asm volatile("s_waitcnt lgkmcnt(0)" ::: "memory");
  asm volatile("s_waitcnt vmcnt(4)" ::: "memory");
  __builtin_amdgcn_s_barrier();
  asm volatile("" ::: "memory");
  PVMFMA(1)
  __builtin_amdgcn_s_barrier();
  asm volatile("" ::: "memory");
  IVC(3, 1)
  EXPWRITE(2)
  asm volatile("s_waitcnt lgkmcnt(0)" ::: "memory");
  asm volatile("s_waitcnt vmcnt(4)" ::: "memory");
  __builtin_amdgcn_s_barrier();
  asm volatile("" ::: "memory");
  PVMFMA(2)
  __builtin_amdgcn_s_barrier();
  asm volatile("" ::: "memory");
  EXPWRITE(3)
  asm volatile("s_waitcnt lgkmcnt(0)" ::: "memory");
  asm volatile("s_waitcnt vmcnt(0)" ::: "memory");
  __builtin_amdgcn_s_barrier();
  asm volatile("" ::: "memory");
  PVMFMA(3)
#undef IVC
#undef EXPWRITE
#undef PVMFMA

#pragma unroll
  for (int fr = 0; fr < 4; ++fr)
#pragma unroll
    for (int i = 0; i < 4; ++i) {
      float s = s4[fr][i];
      s += __shfl_xor(s, 1);
      s += __shfl_xor(s, 2);
      s += __shfl_xor(s, 4);
      s += __shfl_xor(s, 8);
      if (lr == 0) reds[wn * 128 + wm * 64 + fr * 16 + lq * 4 + i] = s;
    }
  asm volatile("s_waitcnt lgkmcnt(0)" ::: "memory");
  __builtin_amdgcn_s_barrier();
  asm volatile("" ::: "memory");

#pragma unroll
  for (int fr = 0; fr < 4; ++fr)
#pragma unroll
    for (int i = 0; i < 4; ++i) {
      const int row = wm * 64 + fr * 16 + lq * 4 + i;
      const float rs = (reds[row] + reds[128 + row]) + (reds[256 + row] + reds[384 + row]);
#pragma unroll
      for (int fc = 0; fc < 2; ++fc) {
        const int col = wn * 32 + fc * 16 + lr;
        Og[((size_t)b * 512 + q0 + row) * 1024 + h * 128 + col] =
            __float2bfloat16(oacc[fr][fc][i] / rs);
      }
    }
}

extern "C" void kernel_launch(void* const* d_in, const int* in_sizes, int n_in,
                              void* d_out, int out_size, void* d_ws, size_t ws_size,
                              hipStream_t stream) {
  (void)in_sizes; (void)n_in; (void)out_size; (void)ws_size;
  const float* x  = (const float*)d_in[0];
  const float* Wq = (const float*)d_in[1];
  const float* bq = (const float*)d_in[2];
  const float* Wk = (const float*)d_in[3];
  const float* bk = (const float*)d_in[4];
  const float* Wv = (const float*)d_in[5];
  const float* bv = (const float*)d_in[6];
  const float* W1 = (const float*)d_in[7];
  const float* b1 = (const float*)d_in[8];
  const float* W2 = (const float*)d_in[9];
  const float* b2 = (const float*)d_in[10];
  float* out = (float*)d_out;
  char* ws = (char*)d_ws;
  constexpr size_t MB = 1ull << 20;

  // workspace layout v2 (R14, lifetimes verified)
  bf16* XB  = (bf16*)(ws + 0);
  bf16* WQT = (bf16*)(ws + 32 * MB);
  bf16* WKT = (bf16*)(ws + 34 * MB);
  bf16* WVT = (bf16*)(ws + 36 * MB);
  bf16* QB  = (bf16*)(ws + 38 * MB);
  bf16* KB  = (bf16*)(ws + 70 * MB);
  bf16* VB  = (bf16*)(ws + 102 * MB);
  bf16* VT  = (bf16*)(ws + 134 * MB);
  bf16* OB  = (bf16*)(ws + 166 * MB);
  bf16* W1T = (bf16*)(ws + 0);
  bf16* W2T = (bf16*)(ws + 16 * MB);
  bf16* HC  = (bf16*)(ws + 38 * MB);
  float* CB = (float*)(ws + 166 * MB);

  k_cvt_bf16<<<2048, 256, 0, stream>>>(x, XB, (16384 * 1024) / 4);
  k_concat_bias<<<12, 256, 0, stream>>>(bq, bk, bv, CB);
  k_transpose_w<<<dim3(32, 32), 256, 0, stream>>>(Wq, WQT, 1024, 1024);
  k_transpose_w<<<dim3(32, 32), 256, 0, stream>>>(Wk, WKT, 1024, 1024);
  k_transpose_w<<<dim3(32, 32), 256, 0, stream>>>(Wv, WVT, 1024, 1024);

  // fused QKV: M=16384, N=3072, K=1024; grid (12, 128) = 1536 wgs (%8==0)
  k_gemm128x256<3, false><<<dim3(12, 128), 256, 0, stream>>>(XB, WQT, CB, QB, 1024, 1024, 1024, 1024);

  k_transpose_w<<<dim3(256, 32), 256, 0, stream>>>(W1, W1T, 1024, 8192);
  k_transpose_w<<<dim3(32, 256), 256, 0, stream>>>(W2, W2T, 8192, 1024);

  k_transpose_v<<<dim3(16, 4, 256), 256, 0, stream>>>(VB, VT);
  k_attn<<<1024, 512, 0, stream>>>(QB, KB, VT, OB);

  // FFN chunked over F (2 x 4096)
  for (int chk = 0; chk < 2; ++chk) {
    k_gemm128x256<1, false><<<dim3(16, 128), 256, 0, stream>>>(
        OB, W1T + (size_t)chk * 4096 * 1024, b1 + chk * 4096, HC, 1024, 1024, 1024, 4096);
    if (chk == 0)
      k_gemm128x256<2, false><<<dim3(4, 128), 256, 0, stream>>>(
          HC, W2T + chk * 4096, b2, out, 4096, 4096, 8192, 1024);
    else
      k_gemm128x256<2, true><<<dim3(4, 128), 256, 0, stream>>>(
          HC, W2T + chk * 4096, nullptr, out, 4096, 4096, 8192, 1024);
  }
}

// Round 16
// 971.350 us; speedup vs baseline: 1.0127x; 1.0127x over previous
//
#include <hip/hip_runtime.h>
#include <hip/hip_bf16.h>
#include <math.h>

typedef __attribute__((ext_vector_type(8))) short bf16x8;
typedef __attribute__((ext_vector_type(4))) float f32x4;
typedef __hip_bfloat16 bf16;

__device__ __forceinline__ void gload_lds16(const void* g, void* l) {
  __builtin_amdgcn_global_load_lds((const __attribute__((address_space(1))) void*)g,
                                   (__attribute__((address_space(3))) void*)l,
                                   16, 0, 0);
}

__device__ __forceinline__ float gelu_erf(float x) {
  return 0.5f * x * (1.0f + erff(x * 0.70710678118654752f));
}

// ---------------- convert f32 -> bf16 (vectorized) ----------------
__global__ __launch_bounds__(256) void k_cvt_bf16(const float* __restrict__ in,
                                                  bf16* __restrict__ out, int n4) {
  int i = blockIdx.x * 256 + threadIdx.x;
  const int stride = gridDim.x * 256;
  for (; i < n4; i += stride) {
    float4 v = reinterpret_cast<const float4*>(in)[i];
    bf16* o = out + (size_t)i * 4;
    o[0] = __float2bfloat16(v.x);
    o[1] = __float2bfloat16(v.y);
    o[2] = __float2bfloat16(v.z);
    o[3] = __float2bfloat16(v.w);
  }
}

// ---------------- concat bq|bk|bv -> cbias[3072] ----------------
__global__ __launch_bounds__(256) void k_concat_bias(const float* __restrict__ bq,
                                                     const float* __restrict__ bk,
                                                     const float* __restrict__ bv,
                                                     float* __restrict__ cbias) {
  const int i = blockIdx.x * 256 + threadIdx.x;  // 0..3071
  const float v = (i < 1024) ? bq[i] : (i < 2048) ? bk[i - 1024] : bv[i - 2048];
  cbias[i] = v;
}

// ---------------- transpose f32 [R][C] -> bf16 [C][R] ----------------
__global__ __launch_bounds__(256) void k_transpose_w(const float* __restrict__ in,
                                                     bf16* __restrict__ out,
                                                     int R, int C) {
  __shared__ float tile[32][33];
  const int c0 = blockIdx.x * 32, r0 = blockIdx.y * 32;
  const int tx = threadIdx.x & 31, ty = threadIdx.x >> 5;
  for (int i = 0; i < 32; i += 8)
    tile[ty + i][tx] = in[(size_t)(r0 + ty + i) * C + c0 + tx];
  __syncthreads();
  for (int i = 0; i < 32; i += 8)
    out[(size_t)(c0 + ty + i) * R + r0 + tx] = __float2bfloat16(tile[tx][ty + i]);
}

// ======== 256x256, BK=64, 8-wave GEMM (R13/R14 schedule, frozen) ========
// EPI: 0=bf16, 1=gelu->bf16, 2=f32(+=ACC), 3=bf16 segmented QKV with fused
// per-head V-transpose: cols<2048 -> Q/K buffers (col>>10); cols>=2048 -> VtOut
// [(b*8+h)*128 + d][s] directly (replaces the separate k_transpose_v pass).
template <int EPI, bool ACC>
__global__ __launch_bounds__(512, 2) void k_gemm256(
    const bf16* __restrict__ A, const bf16* __restrict__ Bt,
    const float* __restrict__ bias, void* __restrict__ Cout,
    bf16* __restrict__ VtOut,
    int K, int lda, int ldb, int ldc) {
  __shared__ __attribute__((aligned(16))) char lds[131072];
  const int t = threadIdx.x, w = t >> 6, l = t & 63;
  const int gx = gridDim.x, nwg = gx * gridDim.y;
  int bid = blockIdx.y * gx + blockIdx.x;
  bid = (bid & 7) * (nwg >> 3) + (bid >> 3);  // XCD swizzle (nwg % 8 == 0)
  const int bm = bid / gx, bn = bid % gx;
  const int wm = w >> 2, wn = w & 3;
  const int lq = l >> 4, lr = l & 15;

  const char* Ab = (const char*)(A + (size_t)(bm * 256) * lda);
  const char* Bb = (const char*)(Bt + (size_t)(bn * 256) * ldb);
  const int r0 = t >> 3, s0x = ((t & 7) ^ (r0 & 7)) << 4;
  const int r1 = (t + 512) >> 3, s1x = (((t + 512) & 7) ^ (r1 & 7)) << 4;
  const size_t la = (size_t)lda * 2, lb = (size_t)ldb * 2;
  const char* pA00 = Ab + (size_t)((r0 >> 6) * 128 + (r0 & 63)) * la + s0x;
  const char* pA10 = Ab + (size_t)((r1 >> 6) * 128 + (r1 & 63)) * la + s1x;
  const char* pA01 = Ab + (size_t)((r0 >> 6) * 128 + 64 + (r0 & 63)) * la + s0x;
  const char* pA11 = Ab + (size_t)((r1 >> 6) * 128 + 64 + (r1 & 63)) * la + s1x;
  const char* pB00 = Bb + (size_t)((r0 >> 5) * 64 + (r0 & 31)) * lb + s0x;
  const char* pB10 = Bb + (size_t)((r1 >> 5) * 64 + (r1 & 31)) * lb + s1x;
  const char* pB01 = Bb + (size_t)((r0 >> 5) * 64 + 32 + (r0 & 31)) * lb + s0x;
  const char* pB11 = Bb + (size_t)((r1 >> 5) * 64 + 32 + (r1 & 31)) * lb + s1x;

  const int swzb = (lq ^ (lr & 7)) << 4;
  const int aoff = wm * 8192 + lr * 128;
  const int boff = 32768 + wn * 4096 + lr * 128;

  f32x4 acc[8][4];
#pragma unroll
  for (int m = 0; m < 8; ++m)
#pragma unroll
    for (int n = 0; n < 4; ++n) acc[m][n] = (f32x4){0.f, 0.f, 0.f, 0.f};

#define ISSUE_A0(S) { gload_lds16(pA00, (S) + w * 1024); gload_lds16(pA10, (S) + 8192 + w * 1024); pA00 += 128; pA10 += 128; }
#define ISSUE_A1(S) { gload_lds16(pA01, (S) + 16384 + w * 1024); gload_lds16(pA11, (S) + 16384 + 8192 + w * 1024); pA01 += 128; pA11 += 128; }
#define ISSUE_B0(S) { gload_lds16(pB00, (S) + 32768 + w * 1024); gload_lds16(pB10, (S) + 32768 + 8192 + w * 1024); pB00 += 128; pB10 += 128; }
#define ISSUE_B1(S) { gload_lds16(pB01, (S) + 49152 + w * 1024); gload_lds16(pB11, (S) + 49152 + 8192 + w * 1024); pB01 += 128; pB11 += 128; }

  bf16x8 aF[4][2], bF01[2][2], bF23[2][2];
#define READ_A03(C) { _Pragma("unroll") for (int fr = 0; fr < 4; ++fr) _Pragma("unroll") for (int kk = 0; kk < 2; ++kk) aF[fr][kk] = *(const bf16x8*)((C) + aoff + fr * 2048 + (swzb ^ (kk << 6))); }
#define READ_A47(C) { _Pragma("unroll") for (int fr = 0; fr < 4; ++fr) _Pragma("unroll") for (int kk = 0; kk < 2; ++kk) aF[fr][kk] = *(const bf16x8*)((C) + 16384 + aoff + fr * 2048 + (swzb ^ (kk << 6))); }
#define READ_B01(C) { _Pragma("unroll") for (int fc = 0; fc < 2; ++fc) _Pragma("unroll") for (int kk = 0; kk < 2; ++kk) bF01[fc][kk] = *(const bf16x8*)((C) + boff + fc * 2048 + (swzb ^ (kk << 6))); }
#define READ_B23(C) { _Pragma("unroll") for (int fc = 0; fc < 2; ++fc) _Pragma("unroll") for (int kk = 0; kk < 2; ++kk) bF23[fc][kk] = *(const bf16x8*)((C) + 16384 + boff + fc * 2048 + (swzb ^ (kk << 6))); }

#define MFMA_Q(ACCR, BFR)                                               \
  { __builtin_amdgcn_s_setprio(1);                                      \
    _Pragma("unroll") for (int fr = 0; fr < 4; ++fr)                    \
      _Pragma("unroll") for (int fc = 0; fc < 2; ++fc)                  \
        _Pragma("unroll") for (int kk = 0; kk < 2; ++kk)                \
          acc[ACCR + fr][fc + ((&BFR == &bF23) ? 2 : 0)] =              \
              __builtin_amdgcn_mfma_f32_16x16x32_bf16(aF[fr][kk], BFR[fc][kk], acc[ACCR + fr][fc + ((&BFR == &bF23) ? 2 : 0)], 0, 0, 0); \
    __builtin_amdgcn_s_setprio(0); }

#define CLOBBER asm volatile("" ::: "memory")
#define BAR __builtin_amdgcn_s_barrier()

  ISSUE_A0(lds); ISSUE_B0(lds); ISSUE_B1(lds); ISSUE_A1(lds);
  asm volatile("s_waitcnt vmcnt(4)" ::: "memory");
  BAR; CLOBBER;

  const int NT = K >> 6;
  for (int kt = 0; kt < NT; ++kt) {
    char* cur = lds + (kt & 1) * 65536;
    char* nxt = lds + ((kt & 1) ^ 1) * 65536;
    const bool pre = (kt + 1 < NT);

    READ_A03(cur); READ_B01(cur);
    if (pre) { ISSUE_A0(nxt);
               asm volatile("s_waitcnt vmcnt(4)" ::: "memory"); }
    else     { asm volatile("s_waitcnt vmcnt(2)" ::: "memory"); }
    BAR; CLOBBER;
    MFMA_Q(0, bF01)
    BAR; CLOBBER;

    READ_B23(cur);
    if (pre) { ISSUE_B0(nxt);
               asm volatile("s_waitcnt vmcnt(4)" ::: "memory"); }
    else     { asm volatile("s_waitcnt vmcnt(0)" ::: "memory"); }
    BAR; CLOBBER;
    MFMA_Q(0, bF23)
    BAR; CLOBBER;

    READ_A47(cur);
    if (pre) ISSUE_B1(nxt);
    CLOBBER;
    BAR; CLOBBER;
    MFMA_Q(4, bF01)
    BAR; CLOBBER;

    if (pre) { ISSUE_A1(nxt);
               asm volatile("s_waitcnt vmcnt(4)" ::: "memory"); }
    else     { CLOBBER; }
    BAR; CLOBBER;
    MFMA_Q(4, bF23)
    BAR; CLOBBER;
  }
#undef ISSUE_A0
#undef ISSUE_A1
#undef ISSUE_B0
#undef ISSUE_B1
#undef READ_A03
#undef READ_A47
#undef READ_B01
#undef READ_B23
#undef MFMA_Q
#undef CLOBBER
#undef BAR

  const int rowb = bm * 256 + wm * 128;
  const int colb = bn * 256 + wn * 64;
#pragma unroll
  for (int fr = 0; fr < 8; ++fr) {
#pragma unroll
    for (int fc = 0; fc < 4; ++fc) {
      const int col = colb + fc * 16 + lr;
      const float bv = bias ? bias[col] : 0.0f;
#pragma unroll
      for (int i = 0; i < 4; ++i) {
        const int row = rowb + fr * 16 + lq * 4 + i;
        float v = acc[fr][fc][i] + bv;
        if (EPI == 1) v = gelu_erf(v);
        if (EPI <= 1) {
          ((bf16*)Cout)[(size_t)row * ldc + col] = __float2bfloat16(v);
        } else if (EPI == 3) {
          if (col < 2048) {
            bf16* Cq = (bf16*)Cout + (size_t)(col >> 10) * 16777216ull;
            Cq[(size_t)row * 1024 + (col & 1023)] = __float2bfloat16(v);
          } else {
            // fused per-head V transpose: VT[((b*8+h)*128 + d)][s]
            const int d = col - 2048;           // 0..1023: h = d>>7, dd = d&127
            const size_t vrow = (size_t)((row >> 9) * 8 + (d >> 7)) * 128 + (d & 127);
            VtOut[vrow * 512 + (row & 511)] = __float2bfloat16(v);
          }
        } else {
          float* Cf = (float*)Cout;
          const size_t idx = (size_t)row * ldc + col;
          if (ACC) v += Cf[idx];
          Cf[idx] = v;
        }
      }
    }
  }
}

// ======== attention v5 (frozen: 133us, VGPR 128) ========
__global__ __launch_bounds__(512, 1) void k_attn(const bf16* __restrict__ Qg,
                                                 const bf16* __restrict__ Kg,
                                                 const bf16* __restrict__ Vt,
                                                 bf16* __restrict__ Og) {
  __shared__ __attribute__((aligned(16))) char lds[131072];
  int bid = blockIdx.x;
  bid = (bid & 7) * 128 + (bid >> 3);  // XCD swizzle, 1024 = 8*128
  const int bh = bid >> 2, q0 = (bid & 3) * 128;
  const int b = bh >> 3, h = bh & 7;
  const int t = threadIdx.x, w = t >> 6, l = t & 63;
  const int lq = l >> 4, lr = l & 15;
  const int wm = w >> 2, wn = w & 3;

  const int sr = t >> 4;
  const int ss = (t & 15) ^ (sr & 15);
  {
    const bf16* ks = Kg + ((size_t)b * 512 + sr) * 1024 + h * 128 + ss * 8;
#pragma unroll
    for (int j = 0; j < 16; ++j)
      gload_lds16(ks + (size_t)j * 32 * 1024, lds + j * 8192 + w * 1024);
  }

  bf16x8 qf[4][4];
  {
    const bf16* qb = Qg + ((size_t)b * 512 + q0 + wm * 64 + lr) * 1024 + h * 128 + lq * 8;
#pragma unroll
    for (int fr = 0; fr < 4; ++fr)
#pragma unroll
      for (int d0 = 0; d0 < 4; ++d0)
        qf[fr][d0] = *(const bf16x8*)(qb + (size_t)(fr * 16) * 1024 + d0 * 32);
  }

  asm volatile("s_waitcnt vmcnt(0)" ::: "memory");
  __builtin_amdgcn_s_barrier();
  asm volatile("" ::: "memory");

  f32x4 accS[4][8];
#pragma unroll
  for (int fr = 0; fr < 4; ++fr)
#pragma unroll
    for (int fc = 0; fc < 8; ++fc) accS[fr][fc] = (f32x4){0.f, 0.f, 0.f, 0.f};

  __builtin_amdgcn_s_setprio(1);
#pragma unroll
  for (int fc = 0; fc < 8; ++fc) {
    bf16x8 kf[4];
#pragma unroll
    for (int d0 = 0; d0 < 4; ++d0)
      kf[d0] = *(const bf16x8*)(lds + (wn * 128 + fc * 16 + lr) * 256 +
                                (((d0 * 4 + lq) ^ lr) << 4));
#pragma unroll
    for (int d0 = 0; d0 < 4; ++d0)
#pragma unroll
      for (int fr = 0; fr < 4; ++fr)
        accS[fr][fc] = __builtin_amdgcn_mfma_f32_16x16x32_bf16(qf[fr][d0], kf[d0], accS[fr][fc], 0, 0, 0);
  }
  __builtin_amdgcn_s_setprio(0);

  __builtin_amdgcn_s_barrier();
  asm volatile("" ::: "memory");

  const bf16* vs = Vt + ((size_t)bh * 128 + sr) * 512 + ss * 8;
#define IVC(kc, slot)                                                         \
  {                                                                           \
    _Pragma("unroll") for (int j = 0; j < 4; ++j)                             \
        gload_lds16(vs + (size_t)j * 32 * 512 + (kc) * 128,                   \
                    lds + (slot) * 32768 + j * 8192 + w * 1024);              \
  }
  IVC(0, 0)
  IVC(1, 1)

  float* redm = (float*)(lds + 98304);
  float* reds = (float*)(lds + 100352);
  float fm[4][4];
#pragma unroll
  for (int fr = 0; fr < 4; ++fr)
#pragma unroll
    for (int i = 0; i < 4; ++i) {
      float m = accS[fr][0][i];
#pragma unroll
      for (int fc = 1; fc < 8; ++fc) m = fmaxf(m, accS[fr][fc][i]);
      m = fmaxf(m, __shfl_xor(m, 1));
      m = fmaxf(m, __shfl_xor(m, 2));
      m = fmaxf(m, __shfl_xor(m, 4));
      m = fmaxf(m, __shfl_xor(m, 8));
      if (lr == 0) redm[wn * 128 + wm * 64 + fr * 16 + lq * 4 + i] = m;
    }
  asm volatile("s_waitcnt lgkmcnt(0)" ::: "memory");
  __builtin_amdgcn_s_barrier();
  asm volatile("" ::: "memory");
#pragma unroll
  for (int fr = 0; fr < 4; ++fr)
#pragma unroll
    for (int i = 0; i < 4; ++i) {
      const int row = wm * 64 + fr * 16 + lq * 4 + i;
      fm[fr][i] = fmaxf(fmaxf(redm[row], redm[128 + row]),
                        fmaxf(redm[256 + row], redm[384 + row]));
    }

  f32x4 oacc[4][2];
#pragma unroll
  for (int fr = 0; fr < 4; ++fr)
#pragma unroll
    for (int fc = 0; fc < 2; ++fc) oacc[fr][fc] = (f32x4){0.f, 0.f, 0.f, 0.f};
  float s4[4][4];
#pragma unroll
  for (int fr = 0; fr < 4; ++fr)
#pragma unroll
    for (int i = 0; i < 4; ++i) s4[fr][i] = 0.f;

#define EXPWRITE(kc)                                                           \
  if (wn == (kc)) {                                                            \
    _Pragma("unroll") for (int fr = 0; fr < 4; ++fr)                           \
      _Pragma("unroll") for (int i = 0; i < 4; ++i) {                          \
        const int row = wm * 64 + fr * 16 + lq * 4 + i;                        \
        const int rx = lq * 4 + i;                                             \
        _Pragma("unroll") for (int fc = 0; fc < 8; ++fc) {                     \
          const float e = __expf(accS[fr][fc][i] - fm[fr][i]);                 \
          s4[fr][i] += e;                                                      \
          *(unsigned short*)(lds + 65536 + row * 256 +                         \
                             (((fc * 2 + (lr >> 3)) ^ rx) << 4) + (lr & 7) * 2) = \
              __bfloat16_as_ushort(__float2bfloat16(e));                       \
        }                                                                      \
      }                                                                        \
  }

#define PVMFMA(kc)                                                             \
  {                                                                            \
    const char* Vb = lds + ((kc) & 1) * 32768;                                 \
    __builtin_amdgcn_s_setprio(1);                                             \
    _Pragma("unroll") for (int kk = 0; kk < 4; ++kk) {                         \
      bf16x8 pa[4], vb[2];                                                     \
      _Pragma("unroll") for (int fr = 0; fr < 4; ++fr)                         \
          pa[fr] = *(const bf16x8*)(lds + 65536 + (wm * 64 + fr * 16 + lr) * 256 + \
                                    (((kk * 4 + lq) ^ lr) << 4));              \
      _Pragma("unroll") for (int fc = 0; fc < 2; ++fc)                         \
          vb[fc] = *(const bf16x8*)(Vb + (wn * 32 + fc * 16 + lr) * 256 +      \
                                    (((kk * 4 + lq) ^ lr) << 4));              \
      _Pragma("unroll") for (int fr = 0; fr < 4; ++fr)                         \
        _Pragma("unroll") for (int fc = 0; fc < 2; ++fc)                       \
          oacc[fr][fc] = __builtin_amdgcn_mfma_f32_16x16x32_bf16(pa[fr], vb[fc], oacc[fr][fc], 0, 0, 0); \
    }                                                                          \
    __builtin_amdgcn_s_setprio(0);                                             \
  }

  EXPWRITE(0)
  asm volatile("s_waitcnt lgkmcnt(0)" ::: "memory");
  asm volatile("s_waitcnt vmcnt(4)" ::: "memory");
  __builtin_amdgcn_s_barrier();
  asm volatile("" ::: "memory");
  PVMFMA(0)
  __builtin_amdgcn_s_barrier();
  asm volatile("" ::: "memory");
  IVC(2, 0)
  EXPWRITE(1)
  asm volatile("s_waitcnt lgkmcnt(0)" ::: "memory");
  asm volatile("s_waitcnt vmcnt(4)" ::: "memory");
  __builtin_amdgcn_s_barrier();
  asm volatile("" ::: "memory");
  PVMFMA(1)
  __builtin_amdgcn_s_barrier();
  asm volatile("" ::: "memory");
  IVC(3, 1)
  EXPWRITE(2)
  asm volatile("s_waitcnt lgkmcnt(0)" ::: "memory");
  asm volatile("s_waitcnt vmcnt(4)" ::: "memory");
  __builtin_amdgcn_s_barrier();
  asm volatile("" ::: "memory");
  PVMFMA(2)
  __builtin_amdgcn_s_barrier();
  asm volatile("" ::: "memory");
  EXPWRITE(3)
  asm volatile("s_waitcnt lgkmcnt(0)" ::: "memory");
  asm volatile("s_waitcnt vmcnt(0)" ::: "memory");
  __builtin_amdgcn_s_barrier();
  asm volatile("" ::: "memory");
  PVMFMA(3)
#undef IVC
#undef EXPWRITE
#undef PVMFMA

#pragma unroll
  for (int fr = 0; fr < 4; ++fr)
#pragma unroll
    for (int i = 0; i < 4; ++i) {
      float s = s4[fr][i];
      s += __shfl_xor(s, 1);
      s += __shfl_xor(s, 2);
      s += __shfl_xor(s, 4);
      s += __shfl_xor(s, 8);
      if (lr == 0) reds[wn * 128 + wm * 64 + fr * 16 + lq * 4 + i] = s;
    }
  asm volatile("s_waitcnt lgkmcnt(0)" ::: "memory");
  __builtin_amdgcn_s_barrier();
  asm volatile("" ::: "memory");

#pragma unroll
  for (int fr = 0; fr < 4; ++fr)
#pragma unroll
    for (int i = 0; i < 4; ++i) {
      const int row = wm * 64 + fr * 16 + lq * 4 + i;
      const float rs = (reds[row] + reds[128 + row]) + (reds[256 + row] + reds[384 + row]);
#pragma unroll
      for (int fc = 0; fc < 2; ++fc) {
        const int col = wn * 32 + fc * 16 + lr;
        Og[((size_t)b * 512 + q0 + row) * 1024 + h * 128 + col] =
            __float2bfloat16(oacc[fr][fc][i] / rs);
      }
    }
}

extern "C" void kernel_launch(void* const* d_in, const int* in_sizes, int n_in,
                              void* d_out, int out_size, void* d_ws, size_t ws_size,
                              hipStream_t stream) {
  (void)in_sizes; (void)n_in; (void)out_size; (void)ws_size;
  const float* x  = (const float*)d_in[0];
  const float* Wq = (const float*)d_in[1];
  const float* bq = (const float*)d_in[2];
  const float* Wk = (const float*)d_in[3];
  const float* bk = (const float*)d_in[4];
  const float* Wv = (const float*)d_in[5];
  const float* bv = (const float*)d_in[6];
  const float* W1 = (const float*)d_in[7];
  const float* b1 = (const float*)d_in[8];
  const float* W2 = (const float*)d_in[9];
  const float* b2 = (const float*)d_in[10];
  float* out = (float*)d_out;
  char* ws = (char*)d_ws;
  constexpr size_t MB = 1ull << 20;

  // workspace layout v2 (R14; VB eliminated — V written directly to VT)
  bf16* XB  = (bf16*)(ws + 0);
  bf16* WQT = (bf16*)(ws + 32 * MB);
  bf16* WKT = (bf16*)(ws + 34 * MB);
  bf16* WVT = (bf16*)(ws + 36 * MB);
  bf16* QB  = (bf16*)(ws + 38 * MB);  // Q 38-70 | K 70-102 (col>>10 routing)
  bf16* VT  = (bf16*)(ws + 134 * MB); // V^T per head, written by QKV epilogue
  bf16* OB  = (bf16*)(ws + 166 * MB);
  bf16* W1T = (bf16*)(ws + 0);        // after QKV (XB dead)
  bf16* W2T = (bf16*)(ws + 16 * MB);
  bf16* HC  = (bf16*)(ws + 38 * MB);  // [16384][4096] overlays dead QKV buffers
  float* CB = (float*)(ws + 166 * MB);

  k_cvt_bf16<<<2048, 256, 0, stream>>>(x, XB, (16384 * 1024) / 4);
  k_concat_bias<<<12, 256, 0, stream>>>(bq, bk, bv, CB);
  k_transpose_w<<<dim3(32, 32), 256, 0, stream>>>(Wq, WQT, 1024, 1024);
  k_transpose_w<<<dim3(32, 32), 256, 0, stream>>>(Wk, WKT, 1024, 1024);
  k_transpose_w<<<dim3(32, 32), 256, 0, stream>>>(Wv, WVT, 1024, 1024);

  // fused QKV: M=16384, N=3072, K=1024; V written transposed (no k_transpose_v)
  k_gemm256<3, false><<<dim3(12, 64), 512, 0, stream>>>(XB, WQT, CB, QB, VT, 1024, 1024, 1024, 1024);

  k_transpose_w<<<dim3(256, 32), 256, 0, stream>>>(W1, W1T, 1024, 8192);
  k_transpose_w<<<dim3(32, 256), 256, 0, stream>>>(W2, W2T, 8192, 1024);

  k_attn<<<1024, 512, 0, stream>>>(QB, QB + 16777216ull, VT, OB);

  // FFN chunked over F (2 x 4096)
  for (int chk = 0; chk < 2; ++chk) {
    k_gemm256<1, false><<<dim3(16, 64), 512, 0, stream>>>(
        OB, W1T + (size_t)chk * 4096 * 1024, b1 + chk * 4096, HC, nullptr, 1024, 1024, 1024, 4096);
    if (chk == 0)
      k_gemm256<2, false><<<dim3(4, 64), 512, 0, stream>>>(
          HC, W2T + chk * 4096, b2, out, nullptr, 4096, 4096, 8192, 1024);
    else
      k_gemm256<2, true><<<dim3(4, 64), 512, 0, stream>>>(
          HC, W2T + chk * 4096, nullptr, out, nullptr, 4096, 4096, 8192, 1024);
  }
}

// Round 17
// 926.318 us; speedup vs baseline: 1.0619x; 1.0486x over previous
//
#include <hip/hip_runtime.h>
#include <hip/hip_bf16.h>
#include <math.h>

typedef __attribute__((ext_vector_type(8))) short bf16x8;
typedef __attribute__((ext_vector_type(4))) float f32x4;
typedef __hip_bfloat16 bf16;

__device__ __forceinline__ void gload_lds16(const void* g, void* l) {
  __builtin_amdgcn_global_load_lds((const __attribute__((address_space(1))) void*)g,
                                   (__attribute__((address_space(3))) void*)l,
                                   16, 0, 0);
}

__device__ __forceinline__ float gelu_erf(float x) {
  return 0.5f * x * (1.0f + erff(x * 0.70710678118654752f));
}

// ---------------- convert f32 -> bf16 (vectorized) ----------------
__global__ __launch_bounds__(256) void k_cvt_bf16(const float* __restrict__ in,
                                                  bf16* __restrict__ out, int n4) {
  int i = blockIdx.x * 256 + threadIdx.x;
  const int stride = gridDim.x * 256;
  for (; i < n4; i += stride) {
    float4 v = reinterpret_cast<const float4*>(in)[i];
    bf16* o = out + (size_t)i * 4;
    o[0] = __float2bfloat16(v.x);
    o[1] = __float2bfloat16(v.y);
    o[2] = __float2bfloat16(v.z);
    o[3] = __float2bfloat16(v.w);
  }
}

// ---------------- concat bq|bk|bv -> cbias[3072] ----------------
__global__ __launch_bounds__(256) void k_concat_bias(const float* __restrict__ bq,
                                                     const float* __restrict__ bk,
                                                     const float* __restrict__ bv,
                                                     float* __restrict__ cbias) {
  const int i = blockIdx.x * 256 + threadIdx.x;  // 0..3071
  const float v = (i < 1024) ? bq[i] : (i < 2048) ? bk[i - 1024] : bv[i - 2048];
  cbias[i] = v;
}

// ---------------- transpose f32 [R][C] -> bf16 [C][R] ----------------
__global__ __launch_bounds__(256) void k_transpose_w(const float* __restrict__ in,
                                                     bf16* __restrict__ out,
                                                     int R, int C) {
  __shared__ float tile[32][33];
  const int c0 = blockIdx.x * 32, r0 = blockIdx.y * 32;
  const int tx = threadIdx.x & 31, ty = threadIdx.x >> 5;
  for (int i = 0; i < 32; i += 8)
    tile[ty + i][tx] = in[(size_t)(r0 + ty + i) * C + c0 + tx];
  __syncthreads();
  for (int i = 0; i < 32; i += 8)
    out[(size_t)(c0 + ty + i) * R + r0 + tx] = __float2bfloat16(tile[tx][ty + i]);
}

// ------------- per-head V transpose: [B*S][E] -> [(b*H+h)*128 + d][S] -------------
__global__ __launch_bounds__(256) void k_transpose_v(const bf16* __restrict__ Vb,
                                                     bf16* __restrict__ Vt) {
  __shared__ bf16 tile[32][34];
  const int bh = blockIdx.z;
  const int b = bh >> 3, h = bh & 7;
  const int s0 = blockIdx.x * 32, d0 = blockIdx.y * 32;
  const int tx = threadIdx.x & 31, ty = threadIdx.x >> 5;
  for (int i = 0; i < 32; i += 8)
    tile[ty + i][tx] = Vb[((size_t)b * 512 + s0 + ty + i) * 1024 + h * 128 + d0 + tx];
  __syncthreads();
  for (int i = 0; i < 32; i += 8)
    Vt[((size_t)bh * 128 + d0 + ty + i) * 512 + s0 + tx] = tile[tx][ty + i];
}

// ======== 256x256, BK=64, 8-wave GEMM (R13 schedule, frozen — best measured) ========
// EPI: 0=bf16, 1=gelu->bf16, 2=f32(+=ACC), 3=bf16 segmented QKV.
template <int EPI, bool ACC>
__global__ __launch_bounds__(512, 2) void k_gemm256(
    const bf16* __restrict__ A, const bf16* __restrict__ Bt,
    const float* __restrict__ bias, void* __restrict__ Cout,
    int K, int lda, int ldb, int ldc) {
  __shared__ __attribute__((aligned(16))) char lds[131072];
  const int t = threadIdx.x, w = t >> 6, l = t & 63;
  const int gx = gridDim.x, nwg = gx * gridDim.y;
  int bid = blockIdx.y * gx + blockIdx.x;
  bid = (bid & 7) * (nwg >> 3) + (bid >> 3);  // XCD swizzle (nwg % 8 == 0)
  const int bm = bid / gx, bn = bid % gx;
  const int wm = w >> 2, wn = w & 3;
  const int lq = l >> 4, lr = l & 15;

  const char* Ab = (const char*)(A + (size_t)(bm * 256) * lda);
  const char* Bb = (const char*)(Bt + (size_t)(bn * 256) * ldb);
  const int r0 = t >> 3, s0x = ((t & 7) ^ (r0 & 7)) << 4;
  const int r1 = (t + 512) >> 3, s1x = (((t + 512) & 7) ^ (r1 & 7)) << 4;
  const size_t la = (size_t)lda * 2, lb = (size_t)ldb * 2;
  const char* pA00 = Ab + (size_t)((r0 >> 6) * 128 + (r0 & 63)) * la + s0x;
  const char* pA10 = Ab + (size_t)((r1 >> 6) * 128 + (r1 & 63)) * la + s1x;
  const char* pA01 = Ab + (size_t)((r0 >> 6) * 128 + 64 + (r0 & 63)) * la + s0x;
  const char* pA11 = Ab + (size_t)((r1 >> 6) * 128 + 64 + (r1 & 63)) * la + s1x;
  const char* pB00 = Bb + (size_t)((r0 >> 5) * 64 + (r0 & 31)) * lb + s0x;
  const char* pB10 = Bb + (size_t)((r1 >> 5) * 64 + (r1 & 31)) * lb + s1x;
  const char* pB01 = Bb + (size_t)((r0 >> 5) * 64 + 32 + (r0 & 31)) * lb + s0x;
  const char* pB11 = Bb + (size_t)((r1 >> 5) * 64 + 32 + (r1 & 31)) * lb + s1x;

  const int swzb = (lq ^ (lr & 7)) << 4;
  const int aoff = wm * 8192 + lr * 128;
  const int boff = 32768 + wn * 4096 + lr * 128;

  f32x4 acc[8][4];
#pragma unroll
  for (int m = 0; m < 8; ++m)
#pragma unroll
    for (int n = 0; n < 4; ++n) acc[m][n] = (f32x4){0.f, 0.f, 0.f, 0.f};

#define ISSUE_A0(S) { gload_lds16(pA00, (S) + w * 1024); gload_lds16(pA10, (S) + 8192 + w * 1024); pA00 += 128; pA10 += 128; }
#define ISSUE_A1(S) { gload_lds16(pA01, (S) + 16384 + w * 1024); gload_lds16(pA11, (S) + 16384 + 8192 + w * 1024); pA01 += 128; pA11 += 128; }
#define ISSUE_B0(S) { gload_lds16(pB00, (S) + 32768 + w * 1024); gload_lds16(pB10, (S) + 32768 + 8192 + w * 1024); pB00 += 128; pB10 += 128; }
#define ISSUE_B1(S) { gload_lds16(pB01, (S) + 49152 + w * 1024); gload_lds16(pB11, (S) + 49152 + 8192 + w * 1024); pB01 += 128; pB11 += 128; }

  bf16x8 aF[4][2], bF01[2][2], bF23[2][2];
#define READ_A03(C) { _Pragma("unroll") for (int fr = 0; fr < 4; ++fr) _Pragma("unroll") for (int kk = 0; kk < 2; ++kk) aF[fr][kk] = *(const bf16x8*)((C) + aoff + fr * 2048 + (swzb ^ (kk << 6))); }
#define READ_A47(C) { _Pragma("unroll") for (int fr = 0; fr < 4; ++fr) _Pragma("unroll") for (int kk = 0; kk < 2; ++kk) aF[fr][kk] = *(const bf16x8*)((C) + 16384 + aoff + fr * 2048 + (swzb ^ (kk << 6))); }
#define READ_B01(C) { _Pragma("unroll") for (int fc = 0; fc < 2; ++fc) _Pragma("unroll") for (int kk = 0; kk < 2; ++kk) bF01[fc][kk] = *(const bf16x8*)((C) + boff + fc * 2048 + (swzb ^ (kk << 6))); }
#define READ_B23(C) { _Pragma("unroll") for (int fc = 0; fc < 2; ++fc) _Pragma("unroll") for (int kk = 0; kk < 2; ++kk) bF23[fc][kk] = *(const bf16x8*)((C) + 16384 + boff + fc * 2048 + (swzb ^ (kk << 6))); }

#define MFMA_Q(ACCR, BFR)                                               \
  { __builtin_amdgcn_s_setprio(1);                                      \
    _Pragma("unroll") for (int fr = 0; fr < 4; ++fr)                    \
      _Pragma("unroll") for (int fc = 0; fc < 2; ++fc)                  \
        _Pragma("unroll") for (int kk = 0; kk < 2; ++kk)                \
          acc[ACCR + fr][fc + ((&BFR == &bF23) ? 2 : 0)] =              \
              __builtin_amdgcn_mfma_f32_16x16x32_bf16(aF[fr][kk], BFR[fc][kk], acc[ACCR + fr][fc + ((&BFR == &bF23) ? 2 : 0)], 0, 0, 0); \
    __builtin_amdgcn_s_setprio(0); }

#define CLOBBER asm volatile("" ::: "memory")
#define BAR __builtin_amdgcn_s_barrier()

  ISSUE_A0(lds); ISSUE_B0(lds); ISSUE_B1(lds); ISSUE_A1(lds);
  asm volatile("s_waitcnt vmcnt(4)" ::: "memory");
  BAR; CLOBBER;

  const int NT = K >> 6;
  for (int kt = 0; kt < NT; ++kt) {
    char* cur = lds + (kt & 1) * 65536;
    char* nxt = lds + ((kt & 1) ^ 1) * 65536;
    const bool pre = (kt + 1 < NT);

    READ_A03(cur); READ_B01(cur);
    if (pre) { ISSUE_A0(nxt);
               asm volatile("s_waitcnt vmcnt(4)" ::: "memory"); }
    else     { asm volatile("s_waitcnt vmcnt(2)" ::: "memory"); }
    BAR; CLOBBER;
    MFMA_Q(0, bF01)
    BAR; CLOBBER;

    READ_B23(cur);
    if (pre) { ISSUE_B0(nxt);
               asm volatile("s_waitcnt vmcnt(4)" ::: "memory"); }
    else     { asm volatile("s_waitcnt vmcnt(0)" ::: "memory"); }
    BAR; CLOBBER;
    MFMA_Q(0, bF23)
    BAR; CLOBBER;

    READ_A47(cur);
    if (pre) ISSUE_B1(nxt);
    CLOBBER;
    BAR; CLOBBER;
    MFMA_Q(4, bF01)
    BAR; CLOBBER;

    if (pre) { ISSUE_A1(nxt);
               asm volatile("s_waitcnt vmcnt(4)" ::: "memory"); }
    else     { CLOBBER; }
    BAR; CLOBBER;
    MFMA_Q(4, bF23)
    BAR; CLOBBER;
  }
#undef ISSUE_A0
#undef ISSUE_A1
#undef ISSUE_B0
#undef ISSUE_B1
#undef READ_A03
#undef READ_A47
#undef READ_B01
#undef READ_B23
#undef MFMA_Q
#undef CLOBBER
#undef BAR

  const int rowb = bm * 256 + wm * 128;
  const int colb = bn * 256 + wn * 64;
#pragma unroll
  for (int fr = 0; fr < 8; ++fr) {
#pragma unroll
    for (int fc = 0; fc < 4; ++fc) {
      const int col = colb + fc * 16 + lr;
      const float bv = bias ? bias[col] : 0.0f;
#pragma unroll
      for (int i = 0; i < 4; ++i) {
        const int row = rowb + fr * 16 + lq * 4 + i;
        float v = acc[fr][fc][i] + bv;
        if (EPI == 1) v = gelu_erf(v);
        if (EPI <= 1) {
          ((bf16*)Cout)[(size_t)row * ldc + col] = __float2bfloat16(v);
        } else if (EPI == 3) {
          bf16* Cq = (bf16*)Cout + (size_t)(colb >> 10) * 16777216ull;
          Cq[(size_t)row * 1024 + (col & 1023)] = __float2bfloat16(v);
        } else {
          float* Cf = (float*)Cout;
          const size_t idx = (size_t)row * ldc + col;
          if (ACC) v += Cf[idx];
          Cf[idx] = v;
        }
      }
    }
  }
}

// ======== attention v5 (frozen: 133us, VGPR 128) ========
__global__ __launch_bounds__(512, 1) void k_attn(const bf16* __restrict__ Qg,
                                                 const bf16* __restrict__ Kg,
                                                 const bf16* __restrict__ Vt,
                                                 bf16* __restrict__ Og) {
  __shared__ __attribute__((aligned(16))) char lds[131072];
  int bid = blockIdx.x;
  bid = (bid & 7) * 128 + (bid >> 3);  // XCD swizzle, 1024 = 8*128
  const int bh = bid >> 2, q0 = (bid & 3) * 128;
  const int b = bh >> 3, h = bh & 7;
  const int t = threadIdx.x, w = t >> 6, l = t & 63;
  const int lq = l >> 4, lr = l & 15;
  const int wm = w >> 2, wn = w & 3;

  const int sr = t >> 4;
  const int ss = (t & 15) ^ (sr & 15);
  {
    const bf16* ks = Kg + ((size_t)b * 512 + sr) * 1024 + h * 128 + ss * 8;
#pragma unroll
    for (int j = 0; j < 16; ++j)
      gload_lds16(ks + (size_t)j * 32 * 1024, lds + j * 8192 + w * 1024);
  }

  bf16x8 qf[4][4];
  {
    const bf16* qb = Qg + ((size_t)b * 512 + q0 + wm * 64 + lr) * 1024 + h * 128 + lq * 8;
#pragma unroll
    for (int fr = 0; fr < 4; ++fr)
#pragma unroll
      for (int d0 = 0; d0 < 4; ++d0)
        qf[fr][d0] = *(const bf16x8*)(qb + (size_t)(fr * 16) * 1024 + d0 * 32);
  }

  asm volatile("s_waitcnt vmcnt(0)" ::: "memory");
  __builtin_amdgcn_s_barrier();
  asm volatile("" ::: "memory");

  f32x4 accS[4][8];
#pragma unroll
  for (int fr = 0; fr < 4; ++fr)
#pragma unroll
    for (int fc = 0; fc < 8; ++fc) accS[fr][fc] = (f32x4){0.f, 0.f, 0.f, 0.f};

  __builtin_amdgcn_s_setprio(1);
#pragma unroll
  for (int fc = 0; fc < 8; ++fc) {
    bf16x8 kf[4];
#pragma unroll
    for (int d0 = 0; d0 < 4; ++d0)
      kf[d0] = *(const bf16x8*)(lds + (wn * 128 + fc * 16 + lr) * 256 +
                                (((d0 * 4 + lq) ^ lr) << 4));
#pragma unroll
    for (int d0 = 0; d0 < 4; ++d0)
#pragma unroll
      for (int fr = 0; fr < 4; ++fr)
        accS[fr][fc] = __builtin_amdgcn_mfma_f32_16x16x32_bf16(qf[fr][d0], kf[d0], accS[fr][fc], 0, 0, 0);
  }
  __builtin_amdgcn_s_setprio(0);

  __builtin_amdgcn_s_barrier();
  asm volatile("" ::: "memory");

  const bf16* vs = Vt + ((size_t)bh * 128 + sr) * 512 + ss * 8;
#define IVC(kc, slot)                                                         \
  {                                                                           \
    _Pragma("unroll") for (int j = 0; j < 4; ++j)                             \
        gload_lds16(vs + (size_t)j * 32 * 512 + (kc) * 128,                   \
                    lds + (slot) * 32768 + j * 8192 + w * 1024);              \
  }
  IVC(0, 0)
  IVC(1, 1)

  float* redm = (float*)(lds + 98304);
  float* reds = (float*)(lds + 100352);
  float fm[4][4];
#pragma unroll
  for (int fr = 0; fr < 4; ++fr)
#pragma unroll
    for (int i = 0; i < 4; ++i) {
      float m = accS[fr][0][i];
#pragma unroll
      for (int fc = 1; fc < 8; ++fc) m = fmaxf(m, accS[fr][fc][i]);
      m = fmaxf(m, __shfl_xor(m, 1));
      m = fmaxf(m, __shfl_xor(m, 2));
      m = fmaxf(m, __shfl_xor(m, 4));
      m = fmaxf(m, __shfl_xor(m, 8));
      if (lr == 0) redm[wn * 128 + wm * 64 + fr * 16 + lq * 4 + i] = m;
    }
  asm volatile("s_waitcnt lgkmcnt(0)" ::: "memory");
  __builtin_amdgcn_s_barrier();
  asm volatile("" ::: "memory");
#pragma unroll
  for (int fr = 0; fr < 4; ++fr)
#pragma unroll
    for (int i = 0; i < 4; ++i) {
      const int row = wm * 64 + fr * 16 + lq * 4 + i;
      fm[fr][i] = fmaxf(fmaxf(redm[row], redm[128 + row]),
                        fmaxf(redm[256 + row], redm[384 + row]));
    }

  f32x4 oacc[4][2];
#pragma unroll
  for (int fr = 0; fr < 4; ++fr)
#pragma unroll
    for (int fc = 0; fc < 2; ++fc) oacc[fr][fc] = (f32x4){0.f, 0.f, 0.f, 0.f};
  float s4[4][4];
#pragma unroll
  for (int fr = 0; fr < 4; ++fr)
#pragma unroll
    for (int i = 0; i < 4; ++i) s4[fr][i] = 0.f;

#define EXPWRITE(kc)                                                           \
  if (wn == (kc)) {                                                            \
    _Pragma("unroll") for (int fr = 0; fr < 4; ++fr)                           \
      _Pragma("unroll") for (int i = 0; i < 4; ++i) {                          \
        const int row = wm * 64 + fr * 16 + lq * 4 + i;                        \
        const int rx = lq * 4 + i;                                             \
        _Pragma("unroll") for (int fc = 0; fc < 8; ++fc) {                     \
          const float e = __expf(accS[fr][fc][i] - fm[fr][i]);                 \
          s4[fr][i] += e;                                                      \
          *(unsigned short*)(lds + 65536 + row * 256 +                         \
                             (((fc * 2 + (lr >> 3)) ^ rx) << 4) + (lr & 7) * 2) = \
              __bfloat16_as_ushort(__float2bfloat16(e));                       \
        }                                                                      \
      }                                                                        \
  }

#define PVMFMA(kc)                                                             \
  {                                                                            \
    const char* Vb = lds + ((kc) & 1) * 32768;                                 \
    __builtin_amdgcn_s_setprio(1);                                             \
    _Pragma("unroll") for (int kk = 0; kk < 4; ++kk) {                         \
      bf16x8 pa[4], vb[2];                                                     \
      _Pragma("unroll") for (int fr = 0; fr < 4; ++fr)                         \
          pa[fr] = *(const bf16x8*)(lds + 65536 + (wm * 64 + fr * 16 + lr) * 256 + \
                                    (((kk * 4 + lq) ^ lr) << 4));              \
      _Pragma("unroll") for (int fc = 0; fc < 2; ++fc)                         \
          vb[fc] = *(const bf16x8*)(Vb + (wn * 32 + fc * 16 + lr) * 256 +      \
                                    (((kk * 4 + lq) ^ lr) << 4));              \
      _Pragma("unroll") for (int fr = 0; fr < 4; ++fr)                         \
        _Pragma("unroll") for (int fc = 0; fc < 2; ++fc)                       \
          oacc[fr][fc] = __builtin_amdgcn_mfma_f32_16x16x32_bf16(pa[fr], vb[fc], oacc[fr][fc], 0, 0, 0); \
    }                                                                          \
    __builtin_amdgcn_s_setprio(0);                                             \
  }

  EXPWRITE(0)
  asm volatile("s_waitcnt lgkmcnt(0)" ::: "memory");
  asm volatile("s_waitcnt vmcnt(4)" ::: "memory");
  __builtin_amdgcn_s_barrier();
  asm volatile("" ::: "memory");
  PVMFMA(0)
  __builtin_amdgcn_s_barrier();
  asm volatile("" ::: "memory");
  IVC(2, 0)
  EXPWRITE(1)
  asm volatile("s_waitcnt lgkmcnt(0)" ::: "memory");
  asm volatile("s_waitcnt vmcnt(4)" ::: "memory");
  __builtin_amdgcn_s_barrier();
  asm volatile("" ::: "memory");
  PVMFMA(1)
  __builtin_amdgcn_s_barrier();
  asm volatile("" ::: "memory");
  IVC(3, 1)
  EXPWRITE(2)
  asm volatile("s_waitcnt lgkmcnt(0)" ::: "memory");
  asm volatile("s_waitcnt vmcnt(4)" ::: "memory");
  __builtin_amdgcn_s_barrier();
  asm volatile("" ::: "memory");
  PVMFMA(2)
  __builtin_amdgcn_s_barrier();
  asm volatile("" ::: "memory");
  EXPWRITE(3)
  asm volatile("s_waitcnt lgkmcnt(0)" ::: "memory");
  asm volatile("s_waitcnt vmcnt(0)" ::: "memory");
  __builtin_amdgcn_s_barrier();
  asm volatile("" ::: "memory");
  PVMFMA(3)
#undef IVC
#undef EXPWRITE
#undef PVMFMA

#pragma unroll
  for (int fr = 0; fr < 4; ++fr)
#pragma unroll
    for (int i = 0; i < 4; ++i) {
      float s = s4[fr][i];
      s += __shfl_xor(s, 1);
      s += __shfl_xor(s, 2);
      s += __shfl_xor(s, 4);
      s += __shfl_xor(s, 8);
      if (lr == 0) reds[wn * 128 + wm * 64 + fr * 16 + lq * 4 + i] = s;
    }
  asm volatile("s_waitcnt lgkmcnt(0)" ::: "memory");
  __builtin_amdgcn_s_barrier();
  asm volatile("" ::: "memory");

#pragma unroll
  for (int fr = 0; fr < 4; ++fr)
#pragma unroll
    for (int i = 0; i < 4; ++i) {
      const int row = wm * 64 + fr * 16 + lq * 4 + i;
      const float rs = (reds[row] + reds[128 + row]) + (reds[256 + row] + reds[384 + row]);
#pragma unroll
      for (int fc = 0; fc < 2; ++fc) {
        const int col = wn * 32 + fc * 16 + lr;
        Og[((size_t)b * 512 + q0 + row) * 1024 + h * 128 + col] =
            __float2bfloat16(oacc[fr][fc][i] / rs);
      }
    }
}

extern "C" void kernel_launch(void* const* d_in, const int* in_sizes, int n_in,
                              void* d_out, int out_size, void* d_ws, size_t ws_size,
                              hipStream_t stream) {
  (void)in_sizes; (void)n_in; (void)out_size; (void)ws_size;
  const float* x  = (const float*)d_in[0];
  const float* Wq = (const float*)d_in[1];
  const float* bq = (const float*)d_in[2];
  const float* Wk = (const float*)d_in[3];
  const float* bk = (const float*)d_in[4];
  const float* Wv = (const float*)d_in[5];
  const float* bv = (const float*)d_in[6];
  const float* W1 = (const float*)d_in[7];
  const float* b1 = (const float*)d_in[8];
  const float* W2 = (const float*)d_in[9];
  const float* b2 = (const float*)d_in[10];
  float* out = (float*)d_out;
  char* ws = (char*)d_ws;
  constexpr size_t MB = 1ull << 20;

  // --- workspace layout v2 (R14, lifetimes verified) ---
  bf16* XB  = (bf16*)(ws + 0);
  bf16* WQT = (bf16*)(ws + 32 * MB);  // WQT/WKT/WVT contiguous = [3072][1024] B^T
  bf16* WKT = (bf16*)(ws + 34 * MB);
  bf16* WVT = (bf16*)(ws + 36 * MB);
  bf16* QB  = (bf16*)(ws + 38 * MB);  // QB/KB/VB contiguous (16M elements apart)
  bf16* KB  = (bf16*)(ws + 70 * MB);
  bf16* VB  = (bf16*)(ws + 102 * MB);
  bf16* VT  = (bf16*)(ws + 134 * MB);
  bf16* OB  = (bf16*)(ws + 166 * MB);
  bf16* W1T = (bf16*)(ws + 0);        // after QKV (XB dead)
  bf16* W2T = (bf16*)(ws + 16 * MB);
  bf16* HC  = (bf16*)(ws + 38 * MB);  // [16384][4096] overlays dead QKV buffers
  float* CB = (float*)(ws + 166 * MB); // bias concat; dead before attn writes OB

  k_cvt_bf16<<<2048, 256, 0, stream>>>(x, XB, (16384 * 1024) / 4);
  k_concat_bias<<<12, 256, 0, stream>>>(bq, bk, bv, CB);
  k_transpose_w<<<dim3(32, 32), 256, 0, stream>>>(Wq, WQT, 1024, 1024);
  k_transpose_w<<<dim3(32, 32), 256, 0, stream>>>(Wk, WKT, 1024, 1024);
  k_transpose_w<<<dim3(32, 32), 256, 0, stream>>>(Wv, WVT, 1024, 1024);

  // fused QKV projection: M=16384, N=3072, K=1024; grid (12,64)=768 wgs (%8==0)
  k_gemm256<3, false><<<dim3(12, 64), 512, 0, stream>>>(XB, WQT, CB, QB, 1024, 1024, 1024, 1024);

  // W1/W2 transposes AFTER QKV so they can overlay the dead XB region
  k_transpose_w<<<dim3(256, 32), 256, 0, stream>>>(W1, W1T, 1024, 8192);
  k_transpose_w<<<dim3(32, 256), 256, 0, stream>>>(W2, W2T, 8192, 1024);

  k_transpose_v<<<dim3(16, 4, 256), 256, 0, stream>>>(VB, VT);
  k_attn<<<1024, 512, 0, stream>>>(QB, KB, VT, OB);

  // FFN chunked over F (2 x 4096)
  for (int chk = 0; chk < 2; ++chk) {
    k_gemm256<1, false><<<dim3(16, 64), 512, 0, stream>>>(
        OB, W1T + (size_t)chk * 4096 * 1024, b1 + chk * 4096, HC, 1024, 1024, 1024, 4096);
    if (chk == 0)
      k_gemm256<2, false><<<dim3(4, 64), 512, 0, stream>>>(
          HC, W2T + chk * 4096, b2, out, 4096, 4096, 8192, 1024);
    else
      k_gemm256<2, true><<<dim3(4, 64), 512, 0, stream>>>(
          HC, W2T + chk * 4096, nullptr, out, 4096, 4096, 8192, 1024);
  }
}

// Round 18
// 910.717 us; speedup vs baseline: 1.0801x; 1.0171x over previous
//
#include <hip/hip_runtime.h>
#include <hip/hip_bf16.h>
#include <math.h>

typedef __attribute__((ext_vector_type(8))) short bf16x8;
typedef __attribute__((ext_vector_type(4))) float f32x4;
typedef __hip_bfloat16 bf16;

__device__ __forceinline__ void gload_lds16(const void* g, void* l) {
  __builtin_amdgcn_global_load_lds((const __attribute__((address_space(1))) void*)g,
                                   (__attribute__((address_space(3))) void*)l,
                                   16, 0, 0);
}

__device__ __forceinline__ float gelu_erf(float x) {
  return 0.5f * x * (1.0f + erff(x * 0.70710678118654752f));
}

// ---------------- convert f32 -> bf16 (vectorized) ----------------
__global__ __launch_bounds__(256) void k_cvt_bf16(const float* __restrict__ in,
                                                  bf16* __restrict__ out, int n4) {
  int i = blockIdx.x * 256 + threadIdx.x;
  const int stride = gridDim.x * 256;
  for (; i < n4; i += stride) {
    float4 v = reinterpret_cast<const float4*>(in)[i];
    bf16* o = out + (size_t)i * 4;
    o[0] = __float2bfloat16(v.x);
    o[1] = __float2bfloat16(v.y);
    o[2] = __float2bfloat16(v.z);
    o[3] = __float2bfloat16(v.w);
  }
}

// ---------------- concat bq|bk|bv -> cbias[3072] ----------------
__global__ __launch_bounds__(256) void k_concat_bias(const float* __restrict__ bq,
                                                     const float* __restrict__ bk,
                                                     const float* __restrict__ bv,
                                                     float* __restrict__ cbias) {
  const int i = blockIdx.x * 256 + threadIdx.x;  // 0..3071
  const float v = (i < 1024) ? bq[i] : (i < 2048) ? bk[i - 1024] : bv[i - 2048];
  cbias[i] = v;
}

// ---------------- transpose f32 [R][C] -> bf16 [C][R] ----------------
__global__ __launch_bounds__(256) void k_transpose_w(const float* __restrict__ in,
                                                     bf16* __restrict__ out,
                                                     int R, int C) {
  __shared__ float tile[32][33];
  const int c0 = blockIdx.x * 32, r0 = blockIdx.y * 32;
  const int tx = threadIdx.x & 31, ty = threadIdx.x >> 5;
  for (int i = 0; i < 32; i += 8)
    tile[ty + i][tx] = in[(size_t)(r0 + ty + i) * C + c0 + tx];
  __syncthreads();
  for (int i = 0; i < 32; i += 8)
    out[(size_t)(c0 + ty + i) * R + r0 + tx] = __float2bfloat16(tile[tx][ty + i]);
}

// ------------- per-head V transpose: [B*S][E] -> [(b*H+h)*128 + d][S] -------------
__global__ __launch_bounds__(256) void k_transpose_v(const bf16* __restrict__ Vb,
                                                     bf16* __restrict__ Vt) {
  __shared__ bf16 tile[32][34];
  const int bh = blockIdx.z;
  const int b = bh >> 3, h = bh & 7;
  const int s0 = blockIdx.x * 32, d0 = blockIdx.y * 32;
  const int tx = threadIdx.x & 31, ty = threadIdx.x >> 5;
  for (int i = 0; i < 32; i += 8)
    tile[ty + i][tx] = Vb[((size_t)b * 512 + s0 + ty + i) * 1024 + h * 128 + d0 + tx];
  __syncthreads();
  for (int i = 0; i < 32; i += 8)
    Vt[((size_t)bh * 128 + d0 + ty + i) * 512 + s0 + tx] = tile[tx][ty + i];
}

// ======== 256x256, BK=64, 8-wave GEMM: DEPTH-2 prefetch via half-tile space reuse ========
// vs R13: issues target tile t+2 into the LDS regions of tile t's same halves,
// right after each half's last read (A0,B0 free after P1; B1 after P2; A1 after P3).
// Issue->use distance 5-7 phases (~1500cy) >> load latency. Waits (oldest-first
// vmcnt ledger): W1@P1=12 (after A0B0(t): B1,A1(t)=4 + t+1's 8), W2@P2=10,
// W3@P3=12 (t+1's 8 + t+2's A0B0 issued at P2); tails 4/2/{8,0}. Prologue stages
// t0+t1 (16 loads). WAR: >=2 barriers between last read and reuse-write issue.
// EPI: 0=bf16, 1=gelu->bf16, 2=f32(+=ACC), 3=bf16 segmented QKV.
template <int EPI, bool ACC>
__global__ __launch_bounds__(512, 2) void k_gemm256(
    const bf16* __restrict__ A, const bf16* __restrict__ Bt,
    const float* __restrict__ bias, void* __restrict__ Cout,
    int K, int lda, int ldb, int ldc) {
  __shared__ __attribute__((aligned(16))) char lds[131072];
  const int t = threadIdx.x, w = t >> 6, l = t & 63;
  const int gx = gridDim.x, nwg = gx * gridDim.y;
  int bid = blockIdx.y * gx + blockIdx.x;
  bid = (bid & 7) * (nwg >> 3) + (bid >> 3);  // XCD swizzle (nwg % 8 == 0)
  const int bm = bid / gx, bn = bid % gx;
  const int wm = w >> 2, wn = w & 3;
  const int lq = l >> 4, lr = l & 15;

  const char* Ab = (const char*)(A + (size_t)(bm * 256) * lda);
  const char* Bb = (const char*)(Bt + (size_t)(bn * 256) * ldb);
  const int r0 = t >> 3, s0x = ((t & 7) ^ (r0 & 7)) << 4;
  const int r1 = (t + 512) >> 3, s1x = (((t + 512) & 7) ^ (r1 & 7)) << 4;
  const size_t la = (size_t)lda * 2, lb = (size_t)ldb * 2;
  const char* pA00 = Ab + (size_t)((r0 >> 6) * 128 + (r0 & 63)) * la + s0x;
  const char* pA10 = Ab + (size_t)((r1 >> 6) * 128 + (r1 & 63)) * la + s1x;
  const char* pA01 = Ab + (size_t)((r0 >> 6) * 128 + 64 + (r0 & 63)) * la + s0x;
  const char* pA11 = Ab + (size_t)((r1 >> 6) * 128 + 64 + (r1 & 63)) * la + s1x;
  const char* pB00 = Bb + (size_t)((r0 >> 5) * 64 + (r0 & 31)) * lb + s0x;
  const char* pB10 = Bb + (size_t)((r1 >> 5) * 64 + (r1 & 31)) * lb + s1x;
  const char* pB01 = Bb + (size_t)((r0 >> 5) * 64 + 32 + (r0 & 31)) * lb + s0x;
  const char* pB11 = Bb + (size_t)((r1 >> 5) * 64 + 32 + (r1 & 31)) * lb + s1x;

  const int swzb = (lq ^ (lr & 7)) << 4;
  const int aoff = wm * 8192 + lr * 128;
  const int boff = 32768 + wn * 4096 + lr * 128;

  f32x4 acc[8][4];
#pragma unroll
  for (int m = 0; m < 8; ++m)
#pragma unroll
    for (int n = 0; n < 4; ++n) acc[m][n] = (f32x4){0.f, 0.f, 0.f, 0.f};

#define ISSUE_A0(S) { gload_lds16(pA00, (S) + w * 1024); gload_lds16(pA10, (S) + 8192 + w * 1024); pA00 += 128; pA10 += 128; }
#define ISSUE_A1(S) { gload_lds16(pA01, (S) + 16384 + w * 1024); gload_lds16(pA11, (S) + 16384 + 8192 + w * 1024); pA01 += 128; pA11 += 128; }
#define ISSUE_B0(S) { gload_lds16(pB00, (S) + 32768 + w * 1024); gload_lds16(pB10, (S) + 32768 + 8192 + w * 1024); pB00 += 128; pB10 += 128; }
#define ISSUE_B1(S) { gload_lds16(pB01, (S) + 49152 + w * 1024); gload_lds16(pB11, (S) + 49152 + 8192 + w * 1024); pB01 += 128; pB11 += 128; }

  bf16x8 aF[4][2], bF01[2][2], bF23[2][2];
#define READ_A03(C) { _Pragma("unroll") for (int fr = 0; fr < 4; ++fr) _Pragma("unroll") for (int kk = 0; kk < 2; ++kk) aF[fr][kk] = *(const bf16x8*)((C) + aoff + fr * 2048 + (swzb ^ (kk << 6))); }
#define READ_A47(C) { _Pragma("unroll") for (int fr = 0; fr < 4; ++fr) _Pragma("unroll") for (int kk = 0; kk < 2; ++kk) aF[fr][kk] = *(const bf16x8*)((C) + 16384 + aoff + fr * 2048 + (swzb ^ (kk << 6))); }
#define READ_B01(C) { _Pragma("unroll") for (int fc = 0; fc < 2; ++fc) _Pragma("unroll") for (int kk = 0; kk < 2; ++kk) bF01[fc][kk] = *(const bf16x8*)((C) + boff + fc * 2048 + (swzb ^ (kk << 6))); }
#define READ_B23(C) { _Pragma("unroll") for (int fc = 0; fc < 2; ++fc) _Pragma("unroll") for (int kk = 0; kk < 2; ++kk) bF23[fc][kk] = *(const bf16x8*)((C) + 16384 + boff + fc * 2048 + (swzb ^ (kk << 6))); }

#define MFMA_Q(ACCR, BFR)                                               \
  { __builtin_amdgcn_s_setprio(1);                                      \
    _Pragma("unroll") for (int fr = 0; fr < 4; ++fr)                    \
      _Pragma("unroll") for (int fc = 0; fc < 2; ++fc)                  \
        _Pragma("unroll") for (int kk = 0; kk < 2; ++kk)                \
          acc[ACCR + fr][fc + ((&BFR == &bF23) ? 2 : 0)] =              \
              __builtin_amdgcn_mfma_f32_16x16x32_bf16(aF[fr][kk], BFR[fc][kk], acc[ACCR + fr][fc + ((&BFR == &bF23) ? 2 : 0)], 0, 0, 0); \
    __builtin_amdgcn_s_setprio(0); }

#define CLOBBER asm volatile("" ::: "memory")
#define BAR __builtin_amdgcn_s_barrier()
#define VMW(n) asm volatile("s_waitcnt vmcnt(" #n ")" ::: "memory")

  // prologue: stage tiles 0 AND 1 fully (16 loads); pointers end at tile 2.
  ISSUE_A0(lds); ISSUE_B0(lds); ISSUE_B1(lds); ISSUE_A1(lds);
  {
    char* s1 = lds + 65536;
    ISSUE_A0(s1); ISSUE_B0(s1); ISSUE_B1(s1); ISSUE_A1(s1);
  }

  const int NT = K >> 6;
  for (int kt = 0; kt < NT; ++kt) {
    char* cur = lds + (kt & 1) * 65536;
    const bool pre1 = (kt + 1 < NT);
    const bool pre2 = (kt + 2 < NT);

    // ---- P1: force A0,B0(kt); read A03,B01; MFMA fr03 x fc01
    if (pre1) { VMW(12); } else { VMW(4); }
    BAR; CLOBBER;
    READ_A03(cur); READ_B01(cur);
    MFMA_Q(0, bF01)
    BAR; CLOBBER;

    // ---- P2: force B1(kt); read B23; issue A0,B0(kt+2) into freed regions
    if (pre1) { VMW(10); } else { VMW(2); }
    BAR; CLOBBER;
    READ_B23(cur);
    if (pre2) { ISSUE_A0(cur); ISSUE_B0(cur); }
    MFMA_Q(0, bF23)
    BAR; CLOBBER;

    // ---- P3: force A1(kt); read A47; issue B1(kt+2)
    if (pre2)      { VMW(12); }
    else if (pre1) { VMW(8); }
    else           { VMW(0); }
    BAR; CLOBBER;
    READ_A47(cur);
    if (pre2) ISSUE_B1(cur);
    MFMA_Q(4, bF01)
    BAR; CLOBBER;

    // ---- P4: issue A1(kt+2); MFMA fr47 x fc23
    if (pre2) ISSUE_A1(cur);
    CLOBBER;
    MFMA_Q(4, bF23)
    BAR; CLOBBER;
  }
#undef ISSUE_A0
#undef ISSUE_A1
#undef ISSUE_B0
#undef ISSUE_B1
#undef READ_A03
#undef READ_A47
#undef READ_B01
#undef READ_B23
#undef MFMA_Q
#undef CLOBBER
#undef BAR
#undef VMW

  const int rowb = bm * 256 + wm * 128;
  const int colb = bn * 256 + wn * 64;
#pragma unroll
  for (int fr = 0; fr < 8; ++fr) {
#pragma unroll
    for (int fc = 0; fc < 4; ++fc) {
      const int col = colb + fc * 16 + lr;
      const float bv = bias ? bias[col] : 0.0f;
#pragma unroll
      for (int i = 0; i < 4; ++i) {
        const int row = rowb + fr * 16 + lq * 4 + i;
        float v = acc[fr][fc][i] + bv;
        if (EPI == 1) v = gelu_erf(v);
        if (EPI <= 1) {
          ((bf16*)Cout)[(size_t)row * ldc + col] = __float2bfloat16(v);
        } else if (EPI == 3) {
          bf16* Cq = (bf16*)Cout + (size_t)(colb >> 10) * 16777216ull;
          Cq[(size_t)row * 1024 + (col & 1023)] = __float2bfloat16(v);
        } else {
          float* Cf = (float*)Cout;
          const size_t idx = (size_t)row * ldc + col;
          if (ACC) v += Cf[idx];
          Cf[idx] = v;
        }
      }
    }
  }
}

// ======== attention v5 (frozen: 133us, VGPR 128) ========
__global__ __launch_bounds__(512, 1) void k_attn(const bf16* __restrict__ Qg,
                                                 const bf16* __restrict__ Kg,
                                                 const bf16* __restrict__ Vt,
                                                 bf16* __restrict__ Og) {
  __shared__ __attribute__((aligned(16))) char lds[131072];
  int bid = blockIdx.x;
  bid = (bid & 7) * 128 + (bid >> 3);  // XCD swizzle, 1024 = 8*128
  const int bh = bid >> 2, q0 = (bid & 3) * 128;
  const int b = bh >> 3, h = bh & 7;
  const int t = threadIdx.x, w = t >> 6, l = t & 63;
  const int lq = l >> 4, lr = l & 15;
  const int wm = w >> 2, wn = w & 3;

  const int sr = t >> 4;
  const int ss = (t & 15) ^ (sr & 15);
  {
    const bf16* ks = Kg + ((size_t)b * 512 + sr) * 1024 + h * 128 + ss * 8;
#pragma unroll
    for (int j = 0; j < 16; ++j)
      gload_lds16(ks + (size_t)j * 32 * 1024, lds + j * 8192 + w * 1024);
  }

  bf16x8 qf[4][4];
  {
    const bf16* qb = Qg + ((size_t)b * 512 + q0 + wm * 64 + lr) * 1024 + h * 128 + lq * 8;
#pragma unroll
    for (int fr = 0; fr < 4; ++fr)
#pragma unroll
      for (int d0 = 0; d0 < 4; ++d0)
        qf[fr][d0] = *(const bf16x8*)(qb + (size_t)(fr * 16) * 1024 + d0 * 32);
  }

  asm volatile("s_waitcnt vmcnt(0)" ::: "memory");
  __builtin_amdgcn_s_barrier();
  asm volatile("" ::: "memory");

  f32x4 accS[4][8];
#pragma unroll
  for (int fr = 0; fr < 4; ++fr)
#pragma unroll
    for (int fc = 0; fc < 8; ++fc) accS[fr][fc] = (f32x4){0.f, 0.f, 0.f, 0.f};

  __builtin_amdgcn_s_setprio(1);
#pragma unroll
  for (int fc = 0; fc < 8; ++fc) {
    bf16x8 kf[4];
#pragma unroll
    for (int d0 = 0; d0 < 4; ++d0)
      kf[d0] = *(const bf16x8*)(lds + (wn * 128 + fc * 16 + lr) * 256 +
                                (((d0 * 4 + lq) ^ lr) << 4));
#pragma unroll
    for (int d0 = 0; d0 < 4; ++d0)
#pragma unroll
      for (int fr = 0; fr < 4; ++fr)
        accS[fr][fc] = __builtin_amdgcn_mfma_f32_16x16x32_bf16(qf[fr][d0], kf[d0], accS[fr][fc], 0, 0, 0);
  }
  __builtin_amdgcn_s_setprio(0);

  __builtin_amdgcn_s_barrier();
  asm volatile("" ::: "memory");

  const bf16* vs = Vt + ((size_t)bh * 128 + sr) * 512 + ss * 8;
#define IVC(kc, slot)                                                         \
  {                                                                           \
    _Pragma("unroll") for (int j = 0; j < 4; ++j)                             \
        gload_lds16(vs + (size_t)j * 32 * 512 + (kc) * 128,                   \
                    lds + (slot) * 32768 + j * 8192 + w * 1024);              \
  }
  IVC(0, 0)
  IVC(1, 1)

  float* redm = (float*)(lds + 98304);
  float* reds = (float*)(lds + 100352);
  float fm[4][4];
#pragma unroll
  for (int fr = 0; fr < 4; ++fr)
#pragma unroll
    for (int i = 0; i < 4; ++i) {
      float m = accS[fr][0][i];
#pragma unroll
      for (int fc = 1; fc < 8; ++fc) m = fmaxf(m, accS[fr][fc][i]);
      m = fmaxf(m, __shfl_xor(m, 1));
      m = fmaxf(m, __shfl_xor(m, 2));
      m = fmaxf(m, __shfl_xor(m, 4));
      m = fmaxf(m, __shfl_xor(m, 8));
      if (lr == 0) redm[wn * 128 + wm * 64 + fr * 16 + lq * 4 + i] = m;
    }
  asm volatile("s_waitcnt lgkmcnt(0)" ::: "memory");
  __builtin_amdgcn_s_barrier();
  asm volatile("" ::: "memory");
#pragma unroll
  for (int fr = 0; fr < 4; ++fr)
#pragma unroll
    for (int i = 0; i < 4; ++i) {
      const int row = wm * 64 + fr * 16 + lq * 4 + i;
      fm[fr][i] = fmaxf(fmaxf(redm[row], redm[128 + row]),
                        fmaxf(redm[256 + row], redm[384 + row]));
    }

  f32x4 oacc[4][2];
#pragma unroll
  for (int fr = 0; fr < 4; ++fr)
#pragma unroll
    for (int fc = 0; fc < 2; ++fc) oacc[fr][fc] = (f32x4){0.f, 0.f, 0.f, 0.f};
  float s4[4][4];
#pragma unroll
  for (int fr = 0; fr < 4; ++fr)
#pragma unroll
    for (int i = 0; i < 4; ++i) s4[fr][i] = 0.f;

#define EXPWRITE(kc)                                                           \
  if (wn == (kc)) {                                                            \
    _Pragma("unroll") for (int fr = 0; fr < 4; ++fr)                           \
      _Pragma("unroll") for (int i = 0; i < 4; ++i) {                          \
        const int row = wm * 64 + fr * 16 + lq * 4 + i;                        \
        const int rx = lq * 4 + i;                                             \
        _Pragma("unroll") for (int fc = 0; fc < 8; ++fc) {                     \
          const float e = __expf(accS[fr][fc][i] - fm[fr][i]);                 \
          s4[fr][i] += e;                                                      \
          *(unsigned short*)(lds + 65536 + row * 256 +                         \
                             (((fc * 2 + (lr >> 3)) ^ rx) << 4) + (lr & 7) * 2) = \
              __bfloat16_as_ushort(__float2bfloat16(e));                       \
        }                                                                      \
      }                                                                        \
  }

#define PVMFMA(kc)                                                             \
  {                                                                            \
    const char* Vb = lds + ((kc) & 1) * 32768;                                 \
    __builtin_amdgcn_s_setprio(1);                                             \
    _Pragma("unroll") for (int kk = 0; kk < 4; ++kk) {                         \
      bf16x8 pa[4], vb[2];                                                     \
      _Pragma("unroll") for (int fr = 0; fr < 4; ++fr)                         \
          pa[fr] = *(const bf16x8*)(lds + 65536 + (wm * 64 + fr * 16 + lr) * 256 + \
                                    (((kk * 4 + lq) ^ lr) << 4));              \
      _Pragma("unroll") for (int fc = 0; fc < 2; ++fc)                         \
          vb[fc] = *(const bf16x8*)(Vb + (wn * 32 + fc * 16 + lr) * 256 +      \
                                    (((kk * 4 + lq) ^ lr) << 4));              \
      _Pragma("unroll") for (int fr = 0; fr < 4; ++fr)                         \
        _Pragma("unroll") for (int fc = 0; fc < 2; ++fc)                       \
          oacc[fr][fc] = __builtin_amdgcn_mfma_f32_16x16x32_bf16(pa[fr], vb[fc], oacc[fr][fc], 0, 0, 0); \
    }                                                                          \
    __builtin_amdgcn_s_setprio(0);                                             \
  }

  EXPWRITE(0)
  asm volatile("s_waitcnt lgkmcnt(0)" ::: "memory");
  asm volatile("s_waitcnt vmcnt(4)" ::: "memory");
  __builtin_amdgcn_s_barrier();
  asm volatile("" ::: "memory");
  PVMFMA(0)
  __builtin_amdgcn_s_barrier();
  asm volatile("" ::: "memory");
  IVC(2, 0)
  EXPWRITE(1)
  asm volatile("s_waitcnt lgkmcnt(0)" ::: "memory");
  asm volatile("s_waitcnt vmcnt(4)" ::: "memory");
  __builtin_amdgcn_s_barrier();
  asm volatile("" ::: "memory");
  PVMFMA(1)
  __builtin_amdgcn_s_barrier();
  asm volatile("" ::: "memory");
  IVC(3, 1)
  EXPWRITE(2)
  asm volatile("s_waitcnt lgkmcnt(0)" ::: "memory");
  asm volatile("s_waitcnt vmcnt(4)" ::: "memory");
  __builtin_amdgcn_s_barrier();
  asm volatile("" ::: "memory");
  PVMFMA(2)
  __builtin_amdgcn_s_barrier();
  asm volatile("" ::: "memory");
  EXPWRITE(3)
  asm volatile("s_waitcnt lgkmcnt(0)" ::: "memory");
  asm volatile("s_waitcnt vmcnt(0)" ::: "memory");
  __builtin_amdgcn_s_barrier();
  asm volatile("" ::: "memory");
  PVMFMA(3)
#undef IVC
#undef EXPWRITE
#undef PVMFMA

#pragma unroll
  for (int fr = 0; fr < 4; ++fr)
#pragma unroll
    for (int i = 0; i < 4; ++i) {
      float s = s4[fr][i];
      s += __shfl_xor(s, 1);
      s += __shfl_xor(s, 2);
      s += __shfl_xor(s, 4);
      s += __shfl_xor(s, 8);
      if (lr == 0) reds[wn * 128 + wm * 64 + fr * 16 + lq * 4 + i] = s;
    }
  asm volatile("s_waitcnt lgkmcnt(0)" ::: "memory");
  __builtin_amdgcn_s_barrier();
  asm volatile("" ::: "memory");

#pragma unroll
  for (int fr = 0; fr < 4; ++fr)
#pragma unroll
    for (int i = 0; i < 4; ++i) {
      const int row = wm * 64 + fr * 16 + lq * 4 + i;
      const float rs = (reds[row] + reds[128 + row]) + (reds[256 + row] + reds[384 + row]);
#pragma unroll
      for (int fc = 0; fc < 2; ++fc) {
        const int col = wn * 32 + fc * 16 + lr;
        Og[((size_t)b * 512 + q0 + row) * 1024 + h * 128 + col] =
            __float2bfloat16(oacc[fr][fc][i] / rs);
      }
    }
}

extern "C" void kernel_launch(void* const* d_in, const int* in_sizes, int n_in,
                              void* d_out, int out_size, void* d_ws, size_t ws_size,
                              hipStream_t stream) {
  (void)in_sizes; (void)n_in; (void)out_size; (void)ws_size;
  const float* x  = (const float*)d_in[0];
  const float* Wq = (const float*)d_in[1];
  const float* bq = (const float*)d_in[2];
  const float* Wk = (const float*)d_in[3];
  const float* bk = (const float*)d_in[4];
  const float* Wv = (const float*)d_in[5];
  const float* bv = (const float*)d_in[6];
  const float* W1 = (const float*)d_in[7];
  const float* b1 = (const float*)d_in[8];
  const float* W2 = (const float*)d_in[9];
  const float* b2 = (const float*)d_in[10];
  float* out = (float*)d_out;
  char* ws = (char*)d_ws;
  constexpr size_t MB = 1ull << 20;

  // workspace layout v2 (R14, lifetimes verified)
  bf16* XB  = (bf16*)(ws + 0);
  bf16* WQT = (bf16*)(ws + 32 * MB);
  bf16* WKT = (bf16*)(ws + 34 * MB);
  bf16* WVT = (bf16*)(ws + 36 * MB);
  bf16* QB  = (bf16*)(ws + 38 * MB);
  bf16* KB  = (bf16*)(ws + 70 * MB);
  bf16* VB  = (bf16*)(ws + 102 * MB);
  bf16* VT  = (bf16*)(ws + 134 * MB);
  bf16* OB  = (bf16*)(ws + 166 * MB);
  bf16* W1T = (bf16*)(ws + 0);
  bf16* W2T = (bf16*)(ws + 16 * MB);
  bf16* HC  = (bf16*)(ws + 38 * MB);
  float* CB = (float*)(ws + 166 * MB);

  k_cvt_bf16<<<2048, 256, 0, stream>>>(x, XB, (16384 * 1024) / 4);
  k_concat_bias<<<12, 256, 0, stream>>>(bq, bk, bv, CB);
  k_transpose_w<<<dim3(32, 32), 256, 0, stream>>>(Wq, WQT, 1024, 1024);
  k_transpose_w<<<dim3(32, 32), 256, 0, stream>>>(Wk, WKT, 1024, 1024);
  k_transpose_w<<<dim3(32, 32), 256, 0, stream>>>(Wv, WVT, 1024, 1024);

  // fused QKV projection: M=16384, N=3072, K=1024; grid (12,64)=768 wgs (%8==0)
  k_gemm256<3, false><<<dim3(12, 64), 512, 0, stream>>>(XB, WQT, CB, QB, 1024, 1024, 1024, 1024);

  k_transpose_w<<<dim3(256, 32), 256, 0, stream>>>(W1, W1T, 1024, 8192);
  k_transpose_w<<<dim3(32, 256), 256, 0, stream>>>(W2, W2T, 8192, 1024);

  k_transpose_v<<<dim3(16, 4, 256), 256, 0, stream>>>(VB, VT);
  k_attn<<<1024, 512, 0, stream>>>(QB, KB, VT, OB);

  // FFN chunked over F (2 x 4096)
  for (int chk = 0; chk < 2; ++chk) {
    k_gemm256<1, false><<<dim3(16, 64), 512, 0, stream>>>(
        OB, W1T + (size_t)chk * 4096 * 1024, b1 + chk * 4096, HC, 1024, 1024, 1024, 4096);
    if (chk == 0)
      k_gemm256<2, false><<<dim3(4, 64), 512, 0, stream>>>(
          HC, W2T + chk * 4096, b2, out, 4096, 4096, 8192, 1024);
    else
      k_gemm256<2, true><<<dim3(4, 64), 512, 0, stream>>>(
          HC, W2T + chk * 4096, nullptr, out, 4096, 4096, 8192, 1024);
  }
}

// Round 20
// 887.241 us; speedup vs baseline: 1.1087x; 1.0265x over previous
//
#include <hip/hip_runtime.h>
#include <hip/hip_bf16.h>
#include <math.h>

typedef __attribute__((ext_vector_type(8))) short bf16x8;
typedef __attribute__((ext_vector_type(4))) float f32x4;
typedef __hip_bfloat16 bf16;

__device__ __forceinline__ void gload_lds16(const void* g, void* l) {
  __builtin_amdgcn_global_load_lds((const __attribute__((address_space(1))) void*)g,
                                   (__attribute__((address_space(3))) void*)l,
                                   16, 0, 0);
}

__device__ __forceinline__ float gelu_erf(float x) {
  return 0.5f * x * (1.0f + erff(x * 0.70710678118654752f));
}

// ---------------- convert f32 -> bf16 (vectorized) ----------------
__global__ __launch_bounds__(256) void k_cvt_bf16(const float* __restrict__ in,
                                                  bf16* __restrict__ out, int n4) {
  int i = blockIdx.x * 256 + threadIdx.x;
  const int stride = gridDim.x * 256;
  for (; i < n4; i += stride) {
    float4 v = reinterpret_cast<const float4*>(in)[i];
    bf16* o = out + (size_t)i * 4;
    o[0] = __float2bfloat16(v.x);
    o[1] = __float2bfloat16(v.y);
    o[2] = __float2bfloat16(v.z);
    o[3] = __float2bfloat16(v.w);
  }
}

// ---------------- concat bq|bk|bv -> cbias[3072] ----------------
__global__ __launch_bounds__(256) void k_concat_bias(const float* __restrict__ bq,
                                                     const float* __restrict__ bk,
                                                     const float* __restrict__ bv,
                                                     float* __restrict__ cbias) {
  const int i = blockIdx.x * 256 + threadIdx.x;  // 0..3071
  const float v = (i < 1024) ? bq[i] : (i < 2048) ? bk[i - 1024] : bv[i - 2048];
  cbias[i] = v;
}

// ---------------- transpose f32 [R][C] -> bf16 [C][R] ----------------
__global__ __launch_bounds__(256) void k_transpose_w(const float* __restrict__ in,
                                                     bf16* __restrict__ out,
                                                     int R, int C) {
  __shared__ float tile[32][33];
  const int c0 = blockIdx.x * 32, r0 = blockIdx.y * 32;
  const int tx = threadIdx.x & 31, ty = threadIdx.x >> 5;
  for (int i = 0; i < 32; i += 8)
    tile[ty + i][tx] = in[(size_t)(r0 + ty + i) * C + c0 + tx];
  __syncthreads();
  for (int i = 0; i < 32; i += 8)
    out[(size_t)(c0 + ty + i) * R + r0 + tx] = __float2bfloat16(tile[tx][ty + i]);
}

// ------------- per-head V transpose: [B*S][E] -> [(b*H+h)*128 + d][S] -------------
__global__ __launch_bounds__(256) void k_transpose_v(const bf16* __restrict__ Vb,
                                                     bf16* __restrict__ Vt) {
  __shared__ bf16 tile[32][34];
  const int bh = blockIdx.z;
  const int b = bh >> 3, h = bh & 7;
  const int s0 = blockIdx.x * 32, d0 = blockIdx.y * 32;
  const int tx = threadIdx.x & 31, ty = threadIdx.x >> 5;
  for (int i = 0; i < 32; i += 8)
    tile[ty + i][tx] = Vb[((size_t)b * 512 + s0 + ty + i) * 1024 + h * 128 + d0 + tx];
  __syncthreads();
  for (int i = 0; i < 32; i += 8)
    Vt[((size_t)bh * 128 + d0 + ty + i) * 512 + s0 + tx] = tile[tx][ty + i];
}

// ======== 256x256, BK=64, 8-wave GEMM: DEPTH-2 prefetch (R18, frozen — best) ========
// EPI: 0=bf16, 1=gelu->bf16, 2=f32(+=ACC), 3=bf16 segmented QKV.
template <int EPI, bool ACC>
__global__ __launch_bounds__(512, 2) void k_gemm256(
    const bf16* __restrict__ A, const bf16* __restrict__ Bt,
    const float* __restrict__ bias, void* __restrict__ Cout,
    int K, int lda, int ldb, int ldc) {
  __shared__ __attribute__((aligned(16))) char lds[131072];
  const int t = threadIdx.x, w = t >> 6, l = t & 63;
  const int gx = gridDim.x, nwg = gx * gridDim.y;
  int bid = blockIdx.y * gx + blockIdx.x;
  bid = (bid & 7) * (nwg >> 3) + (bid >> 3);  // XCD swizzle (nwg % 8 == 0)
  const int bm = bid / gx, bn = bid % gx;
  const int wm = w >> 2, wn = w & 3;
  const int lq = l >> 4, lr = l & 15;

  const char* Ab = (const char*)(A + (size_t)(bm * 256) * lda);
  const char* Bb = (const char*)(Bt + (size_t)(bn * 256) * ldb);
  const int r0 = t >> 3, s0x = ((t & 7) ^ (r0 & 7)) << 4;
  const int r1 = (t + 512) >> 3, s1x = (((t + 512) & 7) ^ (r1 & 7)) << 4;
  const size_t la = (size_t)lda * 2, lb = (size_t)ldb * 2;
  const char* pA00 = Ab + (size_t)((r0 >> 6) * 128 + (r0 & 63)) * la + s0x;
  const char* pA10 = Ab + (size_t)((r1 >> 6) * 128 + (r1 & 63)) * la + s1x;
  const char* pA01 = Ab + (size_t)((r0 >> 6) * 128 + 64 + (r0 & 63)) * la + s0x;
  const char* pA11 = Ab + (size_t)((r1 >> 6) * 128 + 64 + (r1 & 63)) * la + s1x;
  const char* pB00 = Bb + (size_t)((r0 >> 5) * 64 + (r0 & 31)) * lb + s0x;
  const char* pB10 = Bb + (size_t)((r1 >> 5) * 64 + (r1 & 31)) * lb + s1x;
  const char* pB01 = Bb + (size_t)((r0 >> 5) * 64 + 32 + (r0 & 31)) * lb + s0x;
  const char* pB11 = Bb + (size_t)((r1 >> 5) * 64 + 32 + (r1 & 31)) * lb + s1x;

  const int swzb = (lq ^ (lr & 7)) << 4;
  const int aoff = wm * 8192 + lr * 128;
  const int boff = 32768 + wn * 4096 + lr * 128;

  f32x4 acc[8][4];
#pragma unroll
  for (int m = 0; m < 8; ++m)
#pragma unroll
    for (int n = 0; n < 4; ++n) acc[m][n] = (f32x4){0.f, 0.f, 0.f, 0.f};

#define ISSUE_A0(S) { gload_lds16(pA00, (S) + w * 1024); gload_lds16(pA10, (S) + 8192 + w * 1024); pA00 += 128; pA10 += 128; }
#define ISSUE_A1(S) { gload_lds16(pA01, (S) + 16384 + w * 1024); gload_lds16(pA11, (S) + 16384 + 8192 + w * 1024); pA01 += 128; pA11 += 128; }
#define ISSUE_B0(S) { gload_lds16(pB00, (S) + 32768 + w * 1024); gload_lds16(pB10, (S) + 32768 + 8192 + w * 1024); pB00 += 128; pB10 += 128; }
#define ISSUE_B1(S) { gload_lds16(pB01, (S) + 49152 + w * 1024); gload_lds16(pB11, (S) + 49152 + 8192 + w * 1024); pB01 += 128; pB11 += 128; }

  bf16x8 aF[4][2], bF01[2][2], bF23[2][2];
#define READ_A03(C) { _Pragma("unroll") for (int fr = 0; fr < 4; ++fr) _Pragma("unroll") for (int kk = 0; kk < 2; ++kk) aF[fr][kk] = *(const bf16x8*)((C) + aoff + fr * 2048 + (swzb ^ (kk << 6))); }
#define READ_A47(C) { _Pragma("unroll") for (int fr = 0; fr < 4; ++fr) _Pragma("unroll") for (int kk = 0; kk < 2; ++kk) aF[fr][kk] = *(const bf16x8*)((C) + 16384 + aoff + fr * 2048 + (swzb ^ (kk << 6))); }
#define READ_B01(C) { _Pragma("unroll") for (int fc = 0; fc < 2; ++fc) _Pragma("unroll") for (int kk = 0; kk < 2; ++kk) bF01[fc][kk] = *(const bf16x8*)((C) + boff + fc * 2048 + (swzb ^ (kk << 6))); }
#define READ_B23(C) { _Pragma("unroll") for (int fc = 0; fc < 2; ++fc) _Pragma("unroll") for (int kk = 0; kk < 2; ++kk) bF23[fc][kk] = *(const bf16x8*)((C) + 16384 + boff + fc * 2048 + (swzb ^ (kk << 6))); }

#define MFMA_Q(ACCR, BFR)                                               \
  { __builtin_amdgcn_s_setprio(1);                                      \
    _Pragma("unroll") for (int fr = 0; fr < 4; ++fr)                    \
      _Pragma("unroll") for (int fc = 0; fc < 2; ++fc)                  \
        _Pragma("unroll") for (int kk = 0; kk < 2; ++kk)                \
          acc[ACCR + fr][fc + ((&BFR == &bF23) ? 2 : 0)] =              \
              __builtin_amdgcn_mfma_f32_16x16x32_bf16(aF[fr][kk], BFR[fc][kk], acc[ACCR + fr][fc + ((&BFR == &bF23) ? 2 : 0)], 0, 0, 0); \
    __builtin_amdgcn_s_setprio(0); }

#define CLOBBER asm volatile("" ::: "memory")
#define BAR __builtin_amdgcn_s_barrier()
#define VMW(n) asm volatile("s_waitcnt vmcnt(" #n ")" ::: "memory")

  ISSUE_A0(lds); ISSUE_B0(lds); ISSUE_B1(lds); ISSUE_A1(lds);
  {
    char* s1 = lds + 65536;
    ISSUE_A0(s1); ISSUE_B0(s1); ISSUE_B1(s1); ISSUE_A1(s1);
  }

  const int NT = K >> 6;
  for (int kt = 0; kt < NT; ++kt) {
    char* cur = lds + (kt & 1) * 65536;
    const bool pre1 = (kt + 1 < NT);
    const bool pre2 = (kt + 2 < NT);

    if (pre1) { VMW(12); } else { VMW(4); }
    BAR; CLOBBER;
    READ_A03(cur); READ_B01(cur);
    MFMA_Q(0, bF01)
    BAR; CLOBBER;

    if (pre1) { VMW(10); } else { VMW(2); }
    BAR; CLOBBER;
    READ_B23(cur);
    if (pre2) { ISSUE_A0(cur); ISSUE_B0(cur); }
    MFMA_Q(0, bF23)
    BAR; CLOBBER;

    if (pre2)      { VMW(12); }
    else if (pre1) { VMW(8); }
    else           { VMW(0); }
    BAR; CLOBBER;
    READ_A47(cur);
    if (pre2) ISSUE_B1(cur);
    MFMA_Q(4, bF01)
    BAR; CLOBBER;

    if (pre2) ISSUE_A1(cur);
    CLOBBER;
    MFMA_Q(4, bF23)
    BAR; CLOBBER;
  }
#undef ISSUE_A0
#undef ISSUE_A1
#undef ISSUE_B0
#undef ISSUE_B1
#undef READ_A03
#undef READ_A47
#undef READ_B01
#undef READ_B23
#undef MFMA_Q
#undef CLOBBER
#undef BAR
#undef VMW

  const int rowb = bm * 256 + wm * 128;
  const int colb = bn * 256 + wn * 64;
#pragma unroll
  for (int fr = 0; fr < 8; ++fr) {
#pragma unroll
    for (int fc = 0; fc < 4; ++fc) {
      const int col = colb + fc * 16 + lr;
      const float bv = bias ? bias[col] : 0.0f;
#pragma unroll
      for (int i = 0; i < 4; ++i) {
        const int row = rowb + fr * 16 + lq * 4 + i;
        float v = acc[fr][fc][i] + bv;
        if (EPI == 1) v = gelu_erf(v);
        if (EPI <= 1) {
          ((bf16*)Cout)[(size_t)row * ldc + col] = __float2bfloat16(v);
        } else if (EPI == 3) {
          bf16* Cq = (bf16*)Cout + (size_t)(colb >> 10) * 16777216ull;
          Cq[(size_t)row * 1024 + (col & 1023)] = __float2bfloat16(v);
        } else {
          float* Cf = (float*)Cout;
          const size_t idx = (size_t)row * ldc + col;
          if (ACC) v += Cf[idx];
          Cf[idx] = v;
        }
      }
    }
  }
}

// ======== attention v7b: 64 q-rows/block, 64KB LDS, 2 blocks/CU ========
// v7 + RACE FIX: redm/reds (@49152) overlap the K region; a barrier is REQUIRED
// between QKH(1)'s K reads and the redm writes (v7's NaN came from fast waves'
// redm writes corrupting K rows 192-255 while wn=3 was still reading them).
__global__ __launch_bounds__(512, 4) void k_attn(const bf16* __restrict__ Qg,
                                                 const bf16* __restrict__ Kg,
                                                 const bf16* __restrict__ Vt,
                                                 bf16* __restrict__ Og) {
  __shared__ __attribute__((aligned(16))) char lds[65536];
  int bid = blockIdx.x;
  bid = (bid & 7) * 256 + (bid >> 3);  // XCD swizzle, 2048 = 8*256
  const int bh = bid >> 3, q0 = (bid & 7) * 64;
  const int b = bh >> 3, h = bh & 7;
  const int t = threadIdx.x, w = t >> 6, l = t & 63;
  const int lq = l >> 4, lr = l & 15;
  const int wm = w >> 2, wn = w & 3;

  const int sr = t >> 4;
  const int ss = (t & 15) ^ (sr & 15);

  const bf16* ks = Kg + ((size_t)b * 512 + sr) * 1024 + h * 128 + ss * 8;
#define STAGEK(hh)                                                            \
  { _Pragma("unroll") for (int j = 0; j < 8; ++j)                             \
      gload_lds16(ks + (size_t)((hh)*256 + j * 32) * 1024,                    \
                  lds + j * 8192 + w * 1024); }
  STAGEK(0)
  asm volatile("s_waitcnt vmcnt(0)" ::: "memory");
  __builtin_amdgcn_s_barrier();
  asm volatile("" ::: "memory");

  f32x4 accS[2][8];
#pragma unroll
  for (int fr = 0; fr < 2; ++fr)
#pragma unroll
    for (int fc = 0; fc < 8; ++fc) accS[fr][fc] = (f32x4){0.f, 0.f, 0.f, 0.f};

#define QKH(hh)                                                               \
  { const bf16* qb = Qg + ((size_t)b * 512 + q0 + wm * 32 + lr) * 1024 +      \
                     h * 128 + lq * 8;                                        \
    bf16x8 qf[2][4];                                                          \
    _Pragma("unroll") for (int fr = 0; fr < 2; ++fr)                          \
      _Pragma("unroll") for (int d0 = 0; d0 < 4; ++d0)                        \
        qf[fr][d0] = *(const bf16x8*)(qb + (size_t)(fr * 16) * 1024 + d0 * 32); \
    __builtin_amdgcn_s_setprio(1);                                            \
    _Pragma("unroll") for (int fc4 = 0; fc4 < 4; ++fc4) {                     \
      bf16x8 kf[4];                                                           \
      _Pragma("unroll") for (int d0 = 0; d0 < 4; ++d0)                        \
        kf[d0] = *(const bf16x8*)(lds + (wn * 64 + fc4 * 16 + lr) * 256 +     \
                                  (((d0 * 4 + lq) ^ lr) << 4));               \
      _Pragma("unroll") for (int d0 = 0; d0 < 4; ++d0)                        \
        _Pragma("unroll") for (int fr = 0; fr < 2; ++fr)                      \
          accS[fr][(hh)*4 + fc4] = __builtin_amdgcn_mfma_f32_16x16x32_bf16(   \
              qf[fr][d0], kf[d0], accS[fr][(hh)*4 + fc4], 0, 0, 0);           \
    }                                                                         \
    __builtin_amdgcn_s_setprio(0); }

  QKH(0)
  __builtin_amdgcn_s_barrier();
  asm volatile("" ::: "memory");
  STAGEK(1)
  asm volatile("s_waitcnt vmcnt(0)" ::: "memory");
  __builtin_amdgcn_s_barrier();
  asm volatile("" ::: "memory");
  QKH(1)
  // RACE FIX: all K reads must finish before redm/reds (@49152, inside K region)
  // are written below.
  __builtin_amdgcn_s_barrier();
  asm volatile("" ::: "memory");
#undef STAGEK
#undef QKH

  float* redm = (float*)(lds + 49152);  // [4 wn][64 rows]
  float* reds = (float*)(lds + 50176);
#pragma unroll
  for (int fr = 0; fr < 2; ++fr)
#pragma unroll
    for (int i = 0; i < 4; ++i) {
      float m = accS[fr][0][i];
#pragma unroll
      for (int fc = 1; fc < 8; ++fc) m = fmaxf(m, accS[fr][fc][i]);
      m = fmaxf(m, __shfl_xor(m, 1));
      m = fmaxf(m, __shfl_xor(m, 2));
      m = fmaxf(m, __shfl_xor(m, 4));
      m = fmaxf(m, __shfl_xor(m, 8));
      if (lr == 0) redm[wn * 64 + wm * 32 + fr * 16 + lq * 4 + i] = m;
    }
  asm volatile("s_waitcnt lgkmcnt(0)" ::: "memory");
  __builtin_amdgcn_s_barrier();  // redm visible
  asm volatile("" ::: "memory");

  const bf16* vs = Vt + ((size_t)bh * 128 + sr) * 512 + ss * 8;
#define IVC(kc)                                                               \
  { _Pragma("unroll") for (int j = 0; j < 4; ++j)                             \
      gload_lds16(vs + (size_t)(j * 32) * 512 + (kc)*128,                     \
                  lds + j * 8192 + w * 1024); }
  IVC(0)

  float fm[2][4];
#pragma unroll
  for (int fr = 0; fr < 2; ++fr)
#pragma unroll
    for (int i = 0; i < 4; ++i) {
      const int row = wm * 32 + fr * 16 + lq * 4 + i;
      fm[fr][i] = fmaxf(fmaxf(redm[row], redm[64 + row]),
                        fmaxf(redm[128 + row], redm[192 + row]));
    }

  f32x4 oacc[2][2];
#pragma unroll
  for (int fr = 0; fr < 2; ++fr)
#pragma unroll
    for (int fc = 0; fc < 2; ++fc) oacc[fr][fc] = (f32x4){0.f, 0.f, 0.f, 0.f};
  float s4[2][4];
#pragma unroll
  for (int fr = 0; fr < 2; ++fr)
#pragma unroll
    for (int i = 0; i < 4; ++i) s4[fr][i] = 0.f;

#define EXPWRITE(c)                                                            \
  if ((wn >> 1) == ((c)&1)) {                                                  \
    _Pragma("unroll") for (int fr = 0; fr < 2; ++fr)                           \
      _Pragma("unroll") for (int i = 0; i < 4; ++i) {                          \
        const int row = wm * 32 + fr * 16 + lq * 4 + i;                        \
        const int rx = lq * 4 + i;                                             \
        _Pragma("unroll") for (int j = 0; j < 4; ++j) {                        \
          const float e = __expf(accS[fr][((c) >> 1) * 4 + j][i] - fm[fr][i]); \
          s4[fr][i] += e;                                                      \
          const int cs = (wn & 1) * 8 + j * 2 + (lr >> 3);                     \
          *(unsigned short*)(lds + 32768 + row * 256 + ((cs ^ rx) << 4) +      \
                             (lr & 7) * 2) =                                   \
              __bfloat16_as_ushort(__float2bfloat16(e));                       \
        }                                                                      \
      }                                                                        \
  }

#define PVMFMA(c)                                                              \
  {                                                                            \
    __builtin_amdgcn_s_setprio(1);                                             \
    _Pragma("unroll") for (int kk = 0; kk < 4; ++kk) {                         \
      bf16x8 pa[2], vb[2];                                                     \
      _Pragma("unroll") for (int fr = 0; fr < 2; ++fr)                         \
          pa[fr] = *(const bf16x8*)(lds + 32768 + (wm * 32 + fr * 16 + lr) * 256 + \
                                    (((kk * 4 + lq) ^ lr) << 4));              \
      _Pragma("unroll") for (int fc = 0; fc < 2; ++fc)                         \
          vb[fc] = *(const bf16x8*)(lds + (wn * 32 + fc * 16 + lr) * 256 +     \
                                    (((kk * 4 + lq) ^ lr) << 4));              \
      _Pragma("unroll") for (int fr = 0; fr < 2; ++fr)                         \
        _Pragma("unroll") for (int fc = 0; fc < 2; ++fc)                       \
          oacc[fr][fc] = __builtin_amdgcn_mfma_f32_16x16x32_bf16(pa[fr], vb[fc], oacc[fr][fc], 0, 0, 0); \
    }                                                                          \
    __builtin_amdgcn_s_setprio(0);                                             \
  }

#define PVPHASE(c)                                                             \
  EXPWRITE(c)                                                                  \
  asm volatile("s_waitcnt lgkmcnt(0)" ::: "memory");                           \
  asm volatile("s_waitcnt vmcnt(0)" ::: "memory");                             \
  __builtin_amdgcn_s_barrier();                                                \
  asm volatile("" ::: "memory");                                               \
  PVMFMA(c)                                                                    \
  __builtin_amdgcn_s_barrier();                                                \
  asm volatile("" ::: "memory");

  PVPHASE(0)
  IVC(1)
  PVPHASE(1)
  IVC(2)
  PVPHASE(2)
  IVC(3)
  PVPHASE(3)
#undef IVC
#undef EXPWRITE
#undef PVMFMA
#undef PVPHASE

#pragma unroll
  for (int fr = 0; fr < 2; ++fr)
#pragma unroll
    for (int i = 0; i < 4; ++i) {
      float s = s4[fr][i];
      s += __shfl_xor(s, 1);
      s += __shfl_xor(s, 2);
      s += __shfl_xor(s, 4);
      s += __shfl_xor(s, 8);
      if (lr == 0) reds[wn * 64 + wm * 32 + fr * 16 + lq * 4 + i] = s;
    }
  asm volatile("s_waitcnt lgkmcnt(0)" ::: "memory");
  __builtin_amdgcn_s_barrier();
  asm volatile("" ::: "memory");

#pragma unroll
  for (int fr = 0; fr < 2; ++fr)
#pragma unroll
    for (int i = 0; i < 4; ++i) {
      const int row = wm * 32 + fr * 16 + lq * 4 + i;
      const float rs = (reds[row] + reds[64 + row]) + (reds[128 + row] + reds[192 + row]);
#pragma unroll
      for (int fc = 0; fc < 2; ++fc) {
        const int col = wn * 32 + fc * 16 + lr;
        Og[((size_t)b * 512 + q0 + row) * 1024 + h * 128 + col] =
            __float2bfloat16(oacc[fr][fc][i] / rs);
      }
    }
}

extern "C" void kernel_launch(void* const* d_in, const int* in_sizes, int n_in,
                              void* d_out, int out_size, void* d_ws, size_t ws_size,
                              hipStream_t stream) {
  (void)in_sizes; (void)n_in; (void)out_size; (void)ws_size;
  const float* x  = (const float*)d_in[0];
  const float* Wq = (const float*)d_in[1];
  const float* bq = (const float*)d_in[2];
  const float* Wk = (const float*)d_in[3];
  const float* bk = (const float*)d_in[4];
  const float* Wv = (const float*)d_in[5];
  const float* bv = (const float*)d_in[6];
  const float* W1 = (const float*)d_in[7];
  const float* b1 = (const float*)d_in[8];
  const float* W2 = (const float*)d_in[9];
  const float* b2 = (const float*)d_in[10];
  float* out = (float*)d_out;
  char* ws = (char*)d_ws;
  constexpr size_t MB = 1ull << 20;

  // workspace layout v2 (R14, lifetimes verified)
  bf16* XB  = (bf16*)(ws + 0);
  bf16* WQT = (bf16*)(ws + 32 * MB);
  bf16* WKT = (bf16*)(ws + 34 * MB);
  bf16* WVT = (bf16*)(ws + 36 * MB);
  bf16* QB  = (bf16*)(ws + 38 * MB);
  bf16* KB  = (bf16*)(ws + 70 * MB);
  bf16* VB  = (bf16*)(ws + 102 * MB);
  bf16* VT  = (bf16*)(ws + 134 * MB);
  bf16* OB  = (bf16*)(ws + 166 * MB);
  bf16* W1T = (bf16*)(ws + 0);
  bf16* W2T = (bf16*)(ws + 16 * MB);
  bf16* HC  = (bf16*)(ws + 38 * MB);
  float* CB = (float*)(ws + 166 * MB);

  k_cvt_bf16<<<2048, 256, 0, stream>>>(x, XB, (16384 * 1024) / 4);
  k_concat_bias<<<12, 256, 0, stream>>>(bq, bk, bv, CB);
  k_transpose_w<<<dim3(32, 32), 256, 0, stream>>>(Wq, WQT, 1024, 1024);
  k_transpose_w<<<dim3(32, 32), 256, 0, stream>>>(Wk, WKT, 1024, 1024);
  k_transpose_w<<<dim3(32, 32), 256, 0, stream>>>(Wv, WVT, 1024, 1024);

  // fused QKV projection: M=16384, N=3072, K=1024; grid (12,64)=768 wgs (%8==0)
  k_gemm256<3, false><<<dim3(12, 64), 512, 0, stream>>>(XB, WQT, CB, QB, 1024, 1024, 1024, 1024);

  k_transpose_w<<<dim3(256, 32), 256, 0, stream>>>(W1, W1T, 1024, 8192);
  k_transpose_w<<<dim3(32, 256), 256, 0, stream>>>(W2, W2T, 8192, 1024);

  k_transpose_v<<<dim3(16, 4, 256), 256, 0, stream>>>(VB, VT);
  k_attn<<<2048, 512, 0, stream>>>(QB, KB, VT, OB);

  // FFN chunked over F (2 x 4096)
  for (int chk = 0; chk < 2; ++chk) {
    k_gemm256<1, false><<<dim3(16, 64), 512, 0, stream>>>(
        OB, W1T + (size_t)chk * 4096 * 1024, b1 + chk * 4096, HC, 1024, 1024, 1024, 4096);
    if (chk == 0)
      k_gemm256<2, false><<<dim3(4, 64), 512, 0, stream>>>(
          HC, W2T + chk * 4096, b2, out, 4096, 4096, 8192, 1024);
    else
      k_gemm256<2, true><<<dim3(4, 64), 512, 0, stream>>>(
          HC, W2T + chk * 4096, nullptr, out, 4096, 4096, 8192, 1024);
  }
}

// Round 21
// 871.939 us; speedup vs baseline: 1.1282x; 1.0175x over previous
//
#include <hip/hip_runtime.h>
#include <hip/hip_bf16.h>
#include <math.h>

typedef __attribute__((ext_vector_type(8))) short bf16x8;
typedef __attribute__((ext_vector_type(4))) float f32x4;
typedef __hip_bfloat16 bf16;

__device__ __forceinline__ void gload_lds16(const void* g, void* l) {
  __builtin_amdgcn_global_load_lds((const __attribute__((address_space(1))) void*)g,
                                   (__attribute__((address_space(3))) void*)l,
                                   16, 0, 0);
}

__device__ __forceinline__ float gelu_erf(float x) {
  return 0.5f * x * (1.0f + erff(x * 0.70710678118654752f));
}

// ======== fused prologue: cvt x->bf16 | concat bias | Wq/Wk/Wv transpose ========
// block-ID ranges select the job; bodies identical to the proven separate kernels.
// blocks: [0,2048) cvt | [2048,2060) concat | [2060,5132) transpose (3 x 1024)
__global__ __launch_bounds__(256) void k_prologue(
    const float* __restrict__ x, bf16* __restrict__ XB,
    const float* __restrict__ bq, const float* __restrict__ bk,
    const float* __restrict__ bv, float* __restrict__ cbias,
    const float* __restrict__ Wq, const float* __restrict__ Wk,
    const float* __restrict__ Wv, bf16* __restrict__ WT) {
  __shared__ float tile[32][33];
  const int bid = blockIdx.x;
  if (bid < 2048) {
    // ---- cvt f32 -> bf16 (grid-stride over 4M float4) ----
    int i = bid * 256 + threadIdx.x;
    const int stride = 2048 * 256;
    const int n4 = (16384 * 1024) / 4;
    for (; i < n4; i += stride) {
      float4 v = reinterpret_cast<const float4*>(x)[i];
      bf16* o = XB + (size_t)i * 4;
      o[0] = __float2bfloat16(v.x);
      o[1] = __float2bfloat16(v.y);
      o[2] = __float2bfloat16(v.z);
      o[3] = __float2bfloat16(v.w);
    }
  } else if (bid < 2060) {
    // ---- concat bq|bk|bv -> cbias[3072] ----
    const int i = (bid - 2048) * 256 + threadIdx.x;
    const float v = (i < 1024) ? bq[i] : (i < 2048) ? bk[i - 1024] : bv[i - 2048];
    cbias[i] = v;
  } else {
    // ---- transpose one 32x32 tile of Wq/Wk/Wv (R=C=1024) ----
    const int r = bid - 2060;           // 0..3071
    const int wsel = r >> 10;           // 0..2
    const int rr = r & 1023;
    const float* in = (wsel == 0) ? Wq : (wsel == 1) ? Wk : Wv;
    bf16* out = WT + (size_t)wsel * 1048576ull;
    const int c0 = (rr & 31) * 32, r0 = (rr >> 5) * 32;
    const int tx = threadIdx.x & 31, ty = threadIdx.x >> 5;
    for (int i = 0; i < 32; i += 8)
      tile[ty + i][tx] = in[(size_t)(r0 + ty + i) * 1024 + c0 + tx];
    __syncthreads();
    for (int i = 0; i < 32; i += 8)
      out[(size_t)(c0 + ty + i) * 1024 + r0 + tx] = __float2bfloat16(tile[tx][ty + i]);
  }
}

// ---------------- transpose f32 [R][C] -> bf16 [C][R] (W1/W2, post-QKV) ----------------
__global__ __launch_bounds__(256) void k_transpose_w(const float* __restrict__ in,
                                                     bf16* __restrict__ out,
                                                     int R, int C) {
  __shared__ float tile[32][33];
  const int c0 = blockIdx.x * 32, r0 = blockIdx.y * 32;
  const int tx = threadIdx.x & 31, ty = threadIdx.x >> 5;
  for (int i = 0; i < 32; i += 8)
    tile[ty + i][tx] = in[(size_t)(r0 + ty + i) * C + c0 + tx];
  __syncthreads();
  for (int i = 0; i < 32; i += 8)
    out[(size_t)(c0 + ty + i) * R + r0 + tx] = __float2bfloat16(tile[tx][ty + i]);
}

// ------------- per-head V transpose: [B*S][E] -> [(b*H+h)*128 + d][S] -------------
__global__ __launch_bounds__(256) void k_transpose_v(const bf16* __restrict__ Vb,
                                                     bf16* __restrict__ Vt) {
  __shared__ bf16 tile[32][34];
  const int bh = blockIdx.z;
  const int b = bh >> 3, h = bh & 7;
  const int s0 = blockIdx.x * 32, d0 = blockIdx.y * 32;
  const int tx = threadIdx.x & 31, ty = threadIdx.x >> 5;
  for (int i = 0; i < 32; i += 8)
    tile[ty + i][tx] = Vb[((size_t)b * 512 + s0 + ty + i) * 1024 + h * 128 + d0 + tx];
  __syncthreads();
  for (int i = 0; i < 32; i += 8)
    Vt[((size_t)bh * 128 + d0 + ty + i) * 512 + s0 + tx] = tile[tx][ty + i];
}

// ======== 256x256, BK=64, 8-wave GEMM: DEPTH-2 prefetch (R18, frozen — best) ========
// EPI: 0=bf16, 1=gelu->bf16, 2=f32(+=ACC), 3=bf16 segmented QKV.
template <int EPI, bool ACC>
__global__ __launch_bounds__(512, 2) void k_gemm256(
    const bf16* __restrict__ A, const bf16* __restrict__ Bt,
    const float* __restrict__ bias, void* __restrict__ Cout,
    int K, int lda, int ldb, int ldc) {
  __shared__ __attribute__((aligned(16))) char lds[131072];
  const int t = threadIdx.x, w = t >> 6, l = t & 63;
  const int gx = gridDim.x, nwg = gx * gridDim.y;
  int bid = blockIdx.y * gx + blockIdx.x;
  bid = (bid & 7) * (nwg >> 3) + (bid >> 3);  // XCD swizzle (nwg % 8 == 0)
  const int bm = bid / gx, bn = bid % gx;
  const int wm = w >> 2, wn = w & 3;
  const int lq = l >> 4, lr = l & 15;

  const char* Ab = (const char*)(A + (size_t)(bm * 256) * lda);
  const char* Bb = (const char*)(Bt + (size_t)(bn * 256) * ldb);
  const int r0 = t >> 3, s0x = ((t & 7) ^ (r0 & 7)) << 4;
  const int r1 = (t + 512) >> 3, s1x = (((t + 512) & 7) ^ (r1 & 7)) << 4;
  const size_t la = (size_t)lda * 2, lb = (size_t)ldb * 2;
  const char* pA00 = Ab + (size_t)((r0 >> 6) * 128 + (r0 & 63)) * la + s0x;
  const char* pA10 = Ab + (size_t)((r1 >> 6) * 128 + (r1 & 63)) * la + s1x;
  const char* pA01 = Ab + (size_t)((r0 >> 6) * 128 + 64 + (r0 & 63)) * la + s0x;
  const char* pA11 = Ab + (size_t)((r1 >> 6) * 128 + 64 + (r1 & 63)) * la + s1x;
  const char* pB00 = Bb + (size_t)((r0 >> 5) * 64 + (r0 & 31)) * lb + s0x;
  const char* pB10 = Bb + (size_t)((r1 >> 5) * 64 + (r1 & 31)) * lb + s1x;
  const char* pB01 = Bb + (size_t)((r0 >> 5) * 64 + 32 + (r0 & 31)) * lb + s0x;
  const char* pB11 = Bb + (size_t)((r1 >> 5) * 64 + 32 + (r1 & 31)) * lb + s1x;

  const int swzb = (lq ^ (lr & 7)) << 4;
  const int aoff = wm * 8192 + lr * 128;
  const int boff = 32768 + wn * 4096 + lr * 128;

  f32x4 acc[8][4];
#pragma unroll
  for (int m = 0; m < 8; ++m)
#pragma unroll
    for (int n = 0; n < 4; ++n) acc[m][n] = (f32x4){0.f, 0.f, 0.f, 0.f};

#define ISSUE_A0(S) { gload_lds16(pA00, (S) + w * 1024); gload_lds16(pA10, (S) + 8192 + w * 1024); pA00 += 128; pA10 += 128; }
#define ISSUE_A1(S) { gload_lds16(pA01, (S) + 16384 + w * 1024); gload_lds16(pA11, (S) + 16384 + 8192 + w * 1024); pA01 += 128; pA11 += 128; }
#define ISSUE_B0(S) { gload_lds16(pB00, (S) + 32768 + w * 1024); gload_lds16(pB10, (S) + 32768 + 8192 + w * 1024); pB00 += 128; pB10 += 128; }
#define ISSUE_B1(S) { gload_lds16(pB01, (S) + 49152 + w * 1024); gload_lds16(pB11, (S) + 49152 + 8192 + w * 1024); pB01 += 128; pB11 += 128; }

  bf16x8 aF[4][2], bF01[2][2], bF23[2][2];
#define READ_A03(C) { _Pragma("unroll") for (int fr = 0; fr < 4; ++fr) _Pragma("unroll") for (int kk = 0; kk < 2; ++kk) aF[fr][kk] = *(const bf16x8*)((C) + aoff + fr * 2048 + (swzb ^ (kk << 6))); }
#define READ_A47(C) { _Pragma("unroll") for (int fr = 0; fr < 4; ++fr) _Pragma("unroll") for (int kk = 0; kk < 2; ++kk) aF[fr][kk] = *(const bf16x8*)((C) + 16384 + aoff + fr * 2048 + (swzb ^ (kk << 6))); }
#define READ_B01(C) { _Pragma("unroll") for (int fc = 0; fc < 2; ++fc) _Pragma("unroll") for (int kk = 0; kk < 2; ++kk) bF01[fc][kk] = *(const bf16x8*)((C) + boff + fc * 2048 + (swzb ^ (kk << 6))); }
#define READ_B23(C) { _Pragma("unroll") for (int fc = 0; fc < 2; ++fc) _Pragma("unroll") for (int kk = 0; kk < 2; ++kk) bF23[fc][kk] = *(const bf16x8*)((C) + 16384 + boff + fc * 2048 + (swzb ^ (kk << 6))); }

#define MFMA_Q(ACCR, BFR)                                               \
  { __builtin_amdgcn_s_setprio(1);                                      \
    _Pragma("unroll") for (int fr = 0; fr < 4; ++fr)                    \
      _Pragma("unroll") for (int fc = 0; fc < 2; ++fc)                  \
        _Pragma("unroll") for (int kk = 0; kk < 2; ++kk)                \
          acc[ACCR + fr][fc + ((&BFR == &bF23) ? 2 : 0)] =              \
              __builtin_amdgcn_mfma_f32_16x16x32_bf16(aF[fr][kk], BFR[fc][kk], acc[ACCR + fr][fc + ((&BFR == &bF23) ? 2 : 0)], 0, 0, 0); \
    __builtin_amdgcn_s_setprio(0); }

#define CLOBBER asm volatile("" ::: "memory")
#define BAR __builtin_amdgcn_s_barrier()
#define VMW(n) asm volatile("s_waitcnt vmcnt(" #n ")" ::: "memory")

  ISSUE_A0(lds); ISSUE_B0(lds); ISSUE_B1(lds); ISSUE_A1(lds);
  {
    char* s1 = lds + 65536;
    ISSUE_A0(s1); ISSUE_B0(s1); ISSUE_B1(s1); ISSUE_A1(s1);
  }

  const int NT = K >> 6;
  for (int kt = 0; kt < NT; ++kt) {
    char* cur = lds + (kt & 1) * 65536;
    const bool pre1 = (kt + 1 < NT);
    const bool pre2 = (kt + 2 < NT);

    if (pre1) { VMW(12); } else { VMW(4); }
    BAR; CLOBBER;
    READ_A03(cur); READ_B01(cur);
    MFMA_Q(0, bF01)
    BAR; CLOBBER;

    if (pre1) { VMW(10); } else { VMW(2); }
    BAR; CLOBBER;
    READ_B23(cur);
    if (pre2) { ISSUE_A0(cur); ISSUE_B0(cur); }
    MFMA_Q(0, bF23)
    BAR; CLOBBER;

    if (pre2)      { VMW(12); }
    else if (pre1) { VMW(8); }
    else           { VMW(0); }
    BAR; CLOBBER;
    READ_A47(cur);
    if (pre2) ISSUE_B1(cur);
    MFMA_Q(4, bF01)
    BAR; CLOBBER;

    if (pre2) ISSUE_A1(cur);
    CLOBBER;
    MFMA_Q(4, bF23)
    BAR; CLOBBER;
  }
#undef ISSUE_A0
#undef ISSUE_A1
#undef ISSUE_B0
#undef ISSUE_B1
#undef READ_A03
#undef READ_A47
#undef READ_B01
#undef READ_B23
#undef MFMA_Q
#undef CLOBBER
#undef BAR
#undef VMW

  const int rowb = bm * 256 + wm * 128;
  const int colb = bn * 256 + wn * 64;
#pragma unroll
  for (int fr = 0; fr < 8; ++fr) {
#pragma unroll
    for (int fc = 0; fc < 4; ++fc) {
      const int col = colb + fc * 16 + lr;
      const float bv = bias ? bias[col] : 0.0f;
#pragma unroll
      for (int i = 0; i < 4; ++i) {
        const int row = rowb + fr * 16 + lq * 4 + i;
        float v = acc[fr][fc][i] + bv;
        if (EPI == 1) v = gelu_erf(v);
        if (EPI <= 1) {
          ((bf16*)Cout)[(size_t)row * ldc + col] = __float2bfloat16(v);
        } else if (EPI == 3) {
          bf16* Cq = (bf16*)Cout + (size_t)(colb >> 10) * 16777216ull;
          Cq[(size_t)row * 1024 + (col & 1023)] = __float2bfloat16(v);
        } else {
          float* Cf = (float*)Cout;
          const size_t idx = (size_t)row * ldc + col;
          if (ACC) v += Cf[idx];
          Cf[idx] = v;
        }
      }
    }
  }
}

// ======== attention v7b (R20, frozen): 64 q-rows/block, 64KB LDS, 2 blocks/CU ========
__global__ __launch_bounds__(512, 4) void k_attn(const bf16* __restrict__ Qg,
                                                 const bf16* __restrict__ Kg,
                                                 const bf16* __restrict__ Vt,
                                                 bf16* __restrict__ Og) {
  __shared__ __attribute__((aligned(16))) char lds[65536];
  int bid = blockIdx.x;
  bid = (bid & 7) * 256 + (bid >> 3);  // XCD swizzle, 2048 = 8*256
  const int bh = bid >> 3, q0 = (bid & 7) * 64;
  const int b = bh >> 3, h = bh & 7;
  const int t = threadIdx.x, w = t >> 6, l = t & 63;
  const int lq = l >> 4, lr = l & 15;
  const int wm = w >> 2, wn = w & 3;

  const int sr = t >> 4;
  const int ss = (t & 15) ^ (sr & 15);

  const bf16* ks = Kg + ((size_t)b * 512 + sr) * 1024 + h * 128 + ss * 8;
#define STAGEK(hh)                                                            \
  { _Pragma("unroll") for (int j = 0; j < 8; ++j)                             \
      gload_lds16(ks + (size_t)((hh)*256 + j * 32) * 1024,                    \
                  lds + j * 8192 + w * 1024); }
  STAGEK(0)
  asm volatile("s_waitcnt vmcnt(0)" ::: "memory");
  __builtin_amdgcn_s_barrier();
  asm volatile("" ::: "memory");

  f32x4 accS[2][8];
#pragma unroll
  for (int fr = 0; fr < 2; ++fr)
#pragma unroll
    for (int fc = 0; fc < 8; ++fc) accS[fr][fc] = (f32x4){0.f, 0.f, 0.f, 0.f};

#define QKH(hh)                                                               \
  { const bf16* qb = Qg + ((size_t)b * 512 + q0 + wm * 32 + lr) * 1024 +      \
                     h * 128 + lq * 8;                                        \
    bf16x8 qf[2][4];                                                          \
    _Pragma("unroll") for (int fr = 0; fr < 2; ++fr)                          \
      _Pragma("unroll") for (int d0 = 0; d0 < 4; ++d0)                        \
        qf[fr][d0] = *(const bf16x8*)(qb + (size_t)(fr * 16) * 1024 + d0 * 32); \
    __builtin_amdgcn_s_setprio(1);                                            \
    _Pragma("unroll") for (int fc4 = 0; fc4 < 4; ++fc4) {                     \
      bf16x8 kf[4];                                                           \
      _Pragma("unroll") for (int d0 = 0; d0 < 4; ++d0)                        \
        kf[d0] = *(const bf16x8*)(lds + (wn * 64 + fc4 * 16 + lr) * 256 +     \
                                  (((d0 * 4 + lq) ^ lr) << 4));               \
      _Pragma("unroll") for (int d0 = 0; d0 < 4; ++d0)                        \
        _Pragma("unroll") for (int fr = 0; fr < 2; ++fr)                      \
          accS[fr][(hh)*4 + fc4] = __builtin_amdgcn_mfma_f32_16x16x32_bf16(   \
              qf[fr][d0], kf[d0], accS[fr][(hh)*4 + fc4], 0, 0, 0);           \
    }                                                                         \
    __builtin_amdgcn_s_setprio(0); }

  QKH(0)
  __builtin_amdgcn_s_barrier();
  asm volatile("" ::: "memory");
  STAGEK(1)
  asm volatile("s_waitcnt vmcnt(0)" ::: "memory");
  __builtin_amdgcn_s_barrier();
  asm volatile("" ::: "memory");
  QKH(1)
  __builtin_amdgcn_s_barrier();  // RACE FIX: K reads done before redm reuse
  asm volatile("" ::: "memory");
#undef STAGEK
#undef QKH

  float* redm = (float*)(lds + 49152);
  float* reds = (float*)(lds + 50176);
#pragma unroll
  for (int fr = 0; fr < 2; ++fr)
#pragma unroll
    for (int i = 0; i < 4; ++i) {
      float m = accS[fr][0][i];
#pragma unroll
      for (int fc = 1; fc < 8; ++fc) m = fmaxf(m, accS[fr][fc][i]);
      m = fmaxf(m, __shfl_xor(m, 1));
      m = fmaxf(m, __shfl_xor(m, 2));
      m = fmaxf(m, __shfl_xor(m, 4));
      m = fmaxf(m, __shfl_xor(m, 8));
      if (lr == 0) redm[wn * 64 + wm * 32 + fr * 16 + lq * 4 + i] = m;
    }
  asm volatile("s_waitcnt lgkmcnt(0)" ::: "memory");
  __builtin_amdgcn_s_barrier();
  asm volatile("" ::: "memory");

  const bf16* vs = Vt + ((size_t)bh * 128 + sr) * 512 + ss * 8;
#define IVC(kc)                                                               \
  { _Pragma("unroll") for (int j = 0; j < 4; ++j)                             \
      gload_lds16(vs + (size_t)(j * 32) * 512 + (kc)*128,                     \
                  lds + j * 8192 + w * 1024); }
  IVC(0)

  float fm[2][4];
#pragma unroll
  for (int fr = 0; fr < 2; ++fr)
#pragma unroll
    for (int i = 0; i < 4; ++i) {
      const int row = wm * 32 + fr * 16 + lq * 4 + i;
      fm[fr][i] = fmaxf(fmaxf(redm[row], redm[64 + row]),
                        fmaxf(redm[128 + row], redm[192 + row]));
    }

  f32x4 oacc[2][2];
#pragma unroll
  for (int fr = 0; fr < 2; ++fr)
#pragma unroll
    for (int fc = 0; fc < 2; ++fc) oacc[fr][fc] = (f32x4){0.f, 0.f, 0.f, 0.f};
  float s4[2][4];
#pragma unroll
  for (int fr = 0; fr < 2; ++fr)
#pragma unroll
    for (int i = 0; i < 4; ++i) s4[fr][i] = 0.f;

#define EXPWRITE(c)                                                            \
  if ((wn >> 1) == ((c)&1)) {                                                  \
    _Pragma("unroll") for (int fr = 0; fr < 2; ++fr)                           \
      _Pragma("unroll") for (int i = 0; i < 4; ++i) {                          \
        const int row = wm * 32 + fr * 16 + lq * 4 + i;                        \
        const int rx = lq * 4 + i;                                             \
        _Pragma("unroll") for (int j = 0; j < 4; ++j) {                        \
          const float e = __expf(accS[fr][((c) >> 1) * 4 + j][i] - fm[fr][i]); \
          s4[fr][i] += e;                                                      \
          const int cs = (wn & 1) * 8 + j * 2 + (lr >> 3);                     \
          *(unsigned short*)(lds + 32768 + row * 256 + ((cs ^ rx) << 4) +      \
                             (lr & 7) * 2) =                                   \
              __bfloat16_as_ushort(__float2bfloat16(e));                       \
        }                                                                      \
      }                                                                        \
  }

#define PVMFMA(c)                                                              \
  {                                                                            \
    __builtin_amdgcn_s_setprio(1);                                             \
    _Pragma("unroll") for (int kk = 0; kk < 4; ++kk) {                         \
      bf16x8 pa[2], vb[2];                                                     \
      _Pragma("unroll") for (int fr = 0; fr < 2; ++fr)                         \
          pa[fr] = *(const bf16x8*)(lds + 32768 + (wm * 32 + fr * 16 + lr) * 256 + \
                                    (((kk * 4 + lq) ^ lr) << 4));              \
      _Pragma("unroll") for (int fc = 0; fc < 2; ++fc)                         \
          vb[fc] = *(const bf16x8*)(lds + (wn * 32 + fc * 16 + lr) * 256 +     \
                                    (((kk * 4 + lq) ^ lr) << 4));              \
      _Pragma("unroll") for (int fr = 0; fr < 2; ++fr)                         \
        _Pragma("unroll") for (int fc = 0; fc < 2; ++fc)                       \
          oacc[fr][fc] = __builtin_amdgcn_mfma_f32_16x16x32_bf16(pa[fr], vb[fc], oacc[fr][fc], 0, 0, 0); \
    }                                                                          \
    __builtin_amdgcn_s_setprio(0);                                             \
  }

#define PVPHASE(c)                                                             \
  EXPWRITE(c)                                                                  \
  asm volatile("s_waitcnt lgkmcnt(0)" ::: "memory");                           \
  asm volatile("s_waitcnt vmcnt(0)" ::: "memory");                             \
  __builtin_amdgcn_s_barrier();                                                \
  asm volatile("" ::: "memory");                                               \
  PVMFMA(c)                                                                    \
  __builtin_amdgcn_s_barrier();                                                \
  asm volatile("" ::: "memory");

  PVPHASE(0)
  IVC(1)
  PVPHASE(1)
  IVC(2)
  PVPHASE(2)
  IVC(3)
  PVPHASE(3)
#undef IVC
#undef EXPWRITE
#undef PVMFMA
#undef PVPHASE

#pragma unroll
  for (int fr = 0; fr < 2; ++fr)
#pragma unroll
    for (int i = 0; i < 4; ++i) {
      float s = s4[fr][i];
      s += __shfl_xor(s, 1);
      s += __shfl_xor(s, 2);
      s += __shfl_xor(s, 4);
      s += __shfl_xor(s, 8);
      if (lr == 0) reds[wn * 64 + wm * 32 + fr * 16 + lq * 4 + i] = s;
    }
  asm volatile("s_waitcnt lgkmcnt(0)" ::: "memory");
  __builtin_amdgcn_s_barrier();
  asm volatile("" ::: "memory");

#pragma unroll
  for (int fr = 0; fr < 2; ++fr)
#pragma unroll
    for (int i = 0; i < 4; ++i) {
      const int row = wm * 32 + fr * 16 + lq * 4 + i;
      const float rs = (reds[row] + reds[64 + row]) + (reds[128 + row] + reds[192 + row]);
#pragma unroll
      for (int fc = 0; fc < 2; ++fc) {
        const int col = wn * 32 + fc * 16 + lr;
        Og[((size_t)b * 512 + q0 + row) * 1024 + h * 128 + col] =
            __float2bfloat16(oacc[fr][fc][i] / rs);
      }
    }
}

extern "C" void kernel_launch(void* const* d_in, const int* in_sizes, int n_in,
                              void* d_out, int out_size, void* d_ws, size_t ws_size,
                              hipStream_t stream) {
  (void)in_sizes; (void)n_in; (void)out_size; (void)ws_size;
  const float* x  = (const float*)d_in[0];
  const float* Wq = (const float*)d_in[1];
  const float* bq = (const float*)d_in[2];
  const float* Wk = (const float*)d_in[3];
  const float* bk = (const float*)d_in[4];
  const float* Wv = (const float*)d_in[5];
  const float* bv = (const float*)d_in[6];
  const float* W1 = (const float*)d_in[7];
  const float* b1 = (const float*)d_in[8];
  const float* W2 = (const float*)d_in[9];
  const float* b2 = (const float*)d_in[10];
  float* out = (float*)d_out;
  char* ws = (char*)d_ws;
  constexpr size_t MB = 1ull << 20;

  // workspace layout v2 (R14, lifetimes verified)
  bf16* XB  = (bf16*)(ws + 0);
  bf16* WQT = (bf16*)(ws + 32 * MB);  // WQT/WKT/WVT contiguous
  bf16* QB  = (bf16*)(ws + 38 * MB);
  bf16* KB  = (bf16*)(ws + 70 * MB);
  bf16* VB  = (bf16*)(ws + 102 * MB);
  bf16* VT  = (bf16*)(ws + 134 * MB);
  bf16* OB  = (bf16*)(ws + 166 * MB);
  bf16* W1T = (bf16*)(ws + 0);        // after QKV (XB dead)
  bf16* W2T = (bf16*)(ws + 16 * MB);
  bf16* HC  = (bf16*)(ws + 38 * MB);
  float* CB = (float*)(ws + 166 * MB);

  // fused prologue: cvt + bias concat + Wq/Wk/Wv transposes (one launch)
  k_prologue<<<5132, 256, 0, stream>>>(x, XB, bq, bk, bv, CB, Wq, Wk, Wv, WQT);

  // fused QKV projection: M=16384, N=3072, K=1024; grid (12,64)=768 wgs (%8==0)
  k_gemm256<3, false><<<dim3(12, 64), 512, 0, stream>>>(XB, WQT, CB, QB, 1024, 1024, 1024, 1024);

  // W1/W2 transposes AFTER QKV (overlay dead XB region)
  k_transpose_w<<<dim3(256, 32), 256, 0, stream>>>(W1, W1T, 1024, 8192);
  k_transpose_w<<<dim3(32, 256), 256, 0, stream>>>(W2, W2T, 8192, 1024);

  k_transpose_v<<<dim3(16, 4, 256), 256, 0, stream>>>(VB, VT);
  k_attn<<<2048, 512, 0, stream>>>(QB, KB, VT, OB);

  // FFN chunked over F (2 x 4096)
  for (int chk = 0; chk < 2; ++chk) {
    k_gemm256<1, false><<<dim3(16, 64), 512, 0, stream>>>(
        OB, W1T + (size_t)chk * 4096 * 1024, b1 + chk * 4096, HC, 1024, 1024, 1024, 4096);
    if (chk == 0)
      k_gemm256<2, false><<<dim3(4, 64), 512, 0, stream>>>(
          HC, W2T + chk * 4096, b2, out, 4096, 4096, 8192, 1024);
    else
      k_gemm256<2, true><<<dim3(4, 64), 512, 0, stream>>>(
          HC, W2T + chk * 4096, nullptr, out, 4096, 4096, 8192, 1024);
  }
}